// Round 9
// baseline (697.924 us; speedup 1.0000x reference)
//
#include <hip/hip_runtime.h>
#include <hip/hip_bf16.h>

typedef __hip_bfloat16 bf16;
typedef __attribute__((ext_vector_type(8))) short short8;
typedef __attribute__((ext_vector_type(4))) short short4v;
typedef __attribute__((ext_vector_type(4))) float f32x4;

#define MFMA_BF16(a, b, c) __builtin_amdgcn_mfma_f32_16x16x32_bf16((a), (b), (c), 0, 0, 0)

// 1/sqrt(E/H) * log2(e) folded into Wqkv q-rows: softmax exps become plain exp2
#define QSCALE 0.1803368860111270f

__device__ __forceinline__ short f2bf(float f) {
    union { bf16 h; short s; } u;
    u.h = __float2bfloat16(f);
    return u.s;
}

#if defined(__has_builtin) && __has_builtin(__builtin_amdgcn_cvt_pk_bf16_f32)
typedef __attribute__((ext_vector_type(2))) __bf16 bf16x2_t;
__device__ __forceinline__ unsigned int pk2(float a, float b) {
    union { bf16x2_t v; unsigned int u; } x;
    x.v = __builtin_amdgcn_cvt_pk_bf16_f32(a, b);
    return x.u;
}
#else
__device__ __forceinline__ unsigned int pk2(float a, float b) {
    union { bf16 h[2]; unsigned int u; } x;
    x.h[0] = __float2bfloat16(a);
    x.h[1] = __float2bfloat16(b);
    return x.u;
}
#endif

// raw v_exp_f32 (skip LLVM's denormal-range fixup: scores are far from -126)
#if defined(__has_builtin) && __has_builtin(__builtin_amdgcn_exp2f)
#define EXP2F(x) __builtin_amdgcn_exp2f(x)
#else
#define EXP2F(x) exp2f(x)
#endif

// async global->LDS, 16B per lane; dest = wave-uniform base + lane*16 (linear)
__device__ __forceinline__ void gload16(const void* g, void* l) {
    __builtin_amdgcn_global_load_lds(
        (const __attribute__((address_space(1))) unsigned int*)g,
        (__attribute__((address_space(3))) unsigned int*)l, 16, 0, 0);
}

// ---------------- ALL converts in one dispatch (grid.y selects tensor / mode) ----------------
__global__ void cvt_fused(const float* __restrict__ x, const float* __restrict__ y,
                          const float* __restrict__ wo1, const float* __restrict__ wo2,
                          const float* __restrict__ wq1, const float* __restrict__ wq2,
                          bf16* __restrict__ ox, bf16* __restrict__ oy,
                          bf16* __restrict__ oo1, bf16* __restrict__ oo2,
                          bf16* __restrict__ oq1, bf16* __restrict__ oq2) {
    const int yb = blockIdx.y;
    if (yb < 4) {
        int i = blockIdx.x * 256 + threadIdx.x;
        const float* src; bf16* dst; int n4;
        switch (yb) {
            case 0:  src = x;   dst = ox;  n4 = 1048576; break;
            case 1:  src = y;   dst = oy;  n4 = 1048576; break;
            case 2:  src = wo1; dst = oo1; n4 = 262144;  break;
            default: src = wo2; dst = oo2; n4 = 262144;  break;
        }
        if (i >= n4) return;
        float4 f = reinterpret_cast<const float4*>(src)[i];
        short4v s;
        s.x = f2bf(f.x); s.y = f2bf(f.y); s.z = f2bf(f.z); s.w = f2bf(f.w);
        reinterpret_cast<short4v*>(dst)[i] = s;
    } else {
        // dest row n' = comp*1024 + h*64 + d  <-  src row d*48 + comp*16 + h
        const int np = blockIdx.x;
        if (np >= 3072) return;
        const int comp = np >> 10, rem = np & 1023, h = rem >> 6, d = rem & 63;
        const int srow = d * 48 + comp * 16 + h;
        const float* src = ((yb == 5) ? wq2 : wq1) + (long)srow * 1024;
        bf16* dst = ((yb == 5) ? oq2 : oq1) + (long)np * 1024;
        const float sc = (comp == 0) ? QSCALE : 1.0f;
        int t = threadIdx.x;
        float4 f = reinterpret_cast<const float4*>(src)[t];
        short4v s;
        s.x = f2bf(f.x * sc); s.y = f2bf(f.y * sc); s.z = f2bf(f.z * sc); s.w = f2bf(f.w * sc);
        reinterpret_cast<short4v*>(dst)[t] = s;
    }
}

// ---------------- 256x256 qkv GEMM, BK=32, 8 waves of 128x64, 2-buf stage-after-gate ----------------
// LDS-read-BW analysis (R8 post-mortem): 64x64 wave tile reads 8KB LDS per 16 MFMA ->
// pipe-saturated at 845 TF. This kernel: wave tile 128x64 (8x4 frags): 12KB -> 32 MFMA
// (+33% MFMA/LDS-byte). LDS 2 bufs x {A[256][32] + B[256][32]} = 64KB -> 2 blocks/CU.
// Schedule (R5-proven order): gate {vmcnt(0); s_barrier} -> stage tile t+1 (4 gloads/wave)
// -> read 12 frags -> 32 MFMA. Drain is free: tile t's loads issued a FULL iter (~1500cyc)
// earlier. Race-free: stage(t+1)->buf(t-1); its readers (compute t-1) drained lgkmcnt
// before the barrier all waves just passed. Swizzle both-sides (row>>1)&3 (R8-verified).
// Epilogue: x<4 -> q packed [bh][t][d], 4..7 -> k, 8..11 -> LDS-transpose V -> [bh][d][t].
__global__ __launch_bounds__(512, 4)
void gemm_qkv256(const bf16* __restrict__ A0g, const bf16* __restrict__ B0g,
                 void* o0a, void* o0b, void* o0c,
                 const bf16* __restrict__ A1g, const bf16* __restrict__ B1g,
                 void* o1a, void* o1b, void* o1c) {
    extern __shared__ short smem[];   // 32768 shorts = 64KB (2 bufs x 16384)
    const int z = blockIdx.z;
    const short* A = reinterpret_cast<const short*>(z ? A1g : A0g);
    const short* B = reinterpret_cast<const short*>(z ? B1g : B0g);
    const int tid  = threadIdx.x;
    const int lane = tid & 63;
    const int w    = tid >> 6;        // 0..7
    const int quad = lane >> 4;
    const int l16  = lane & 15;
    const long M0 = (long)blockIdx.y * 256;
    const long N0 = (long)blockIdx.x * 256;

    const int wm = w >> 2;            // wave M-half (0..1), 128 rows
    const int wn = w & 3;             // wave N-group (0..3), 64 cols
    const int cA0  = (quad ^ ((l16 >> 1) & 3)) * 8;     // read slot (h = row bits 1-2)
    const int aoff = wm * 4096 + l16 * 32;              // A row base (shorts, within buf)
    const int boff = 8192 + wn * 2048 + l16 * 32;       // B row base within buf

    // staging: 4 lanes/row (4 chunks x 16B = 64B row), 16 rows per gload16;
    // wave w stages A rows 32w..32w+31 and B rows 32w..32w+31 (2 gloads each)
    const int srow = lane >> 2;                          // 0..15
    const int scs  = ((lane & 3) ^ ((srow >> 1) & 3)) * 8;  // swizzled source chunk
    const short* Asrc = A + (M0 + 32 * w + srow) * 1024 + scs;
    const short* Bsrc = B + (N0 + 32 * w + srow) * 1024 + scs;

    f32x4 acc[8][4] = {};
    short8 af[8], bfv[4];

#define STG(tt, nbase) do { \
    const short* _a = Asrc + (tt) * 32; \
    const short* _b = Bsrc + (tt) * 32; \
    short* _da = smem + (nbase) + w * 1024; \
    short* _db = _da + 8192; \
    gload16(_a, _da); gload16(_a + 16384, _da + 512); \
    gload16(_b, _db); gload16(_b + 16384, _db + 512); } while (0)
#define RDALL(bbv) do { \
    _Pragma("unroll") for (int mt = 0; mt < 8; ++mt) \
        af[mt] = *reinterpret_cast<const short8*>(&smem[(bbv) + aoff + mt * 512 + cA0]); \
    _Pragma("unroll") for (int nt = 0; nt < 4; ++nt) \
        bfv[nt] = *reinterpret_cast<const short8*>(&smem[(bbv) + boff + nt * 512 + cA0]); } while (0)
#define MMALL() do { \
    __builtin_amdgcn_s_setprio(1); \
    _Pragma("unroll") for (int mt = 0; mt < 8; ++mt) \
    _Pragma("unroll") for (int nt = 0; nt < 4; ++nt) \
        acc[mt][nt] = MFMA_BF16(af[mt], bfv[nt], acc[mt][nt]); \
    __builtin_amdgcn_s_setprio(0); } while (0)

    // prologue: tile 0 -> buf 0
    STG(0, 0);

#pragma unroll 1
    for (int t = 0; t < 32; ++t) {
        // gate: drains tile t's loads (issued a full iter earlier -> free)
        asm volatile("s_waitcnt vmcnt(0)" ::: "memory");
        __builtin_amdgcn_s_barrier();
        __builtin_amdgcn_sched_barrier(0);
        if (t < 31) STG(t + 1, ((t + 1) & 1) << 14);
        const int bb = (t & 1) << 14;
        RDALL(bb);
        MMALL();
    }

    __syncthreads();   // epilogue ws scratch overlaps buf1 (wave 7's region)

    if (blockIdx.x < 8) {
        // q (x<4) / k (x 4..7), packed [bh][t][d]
        short* dst = reinterpret_cast<short*>(blockIdx.x < 4 ? (z ? o1a : o0a)
                                                             : (z ? o1b : o0b));
        const int b = (int)(M0 >> 10);
        const int t00 = ((int)M0 & 1023) + wm * 128 + quad * 4;
        const int hd00 = ((int)blockIdx.x & 3) * 256 + wn * 64;
#pragma unroll
        for (int nt = 0; nt < 4; ++nt) {
            const int hd = hd00 + nt * 16 + l16;
            const int h = hd >> 6, d = hd & 63;
            short* dp = dst + (long)(b * 16 + h) * 65536 + d;
#pragma unroll
            for (int mt = 0; mt < 8; ++mt)
#pragma unroll
                for (int r = 0; r < 4; ++r)
                    dp[(long)(t00 + mt * 16 + r) * 64] = f2bf(acc[mt][nt][r]);
        }
    } else {
        // V: per-wave LDS transpose -> vT [bh][d][t]; 4 passes of 64t x 32hd
        short* vT = reinterpret_cast<short*>(z ? o1c : o0c);
        const int b = (int)(M0 >> 10);
        short* ws = smem + w * 2304;     // 32 cols x 72 shorts, wave-private
        const int c8 = (lane & 7) * 8;
        const int colr = lane >> 3;
#pragma unroll
        for (int ph = 0; ph < 4; ++ph) {
            const int mh = ph >> 1, np = ph & 1;
#pragma unroll
            for (int ntl = 0; ntl < 2; ++ntl)
#pragma unroll
                for (int mtl = 0; mtl < 4; ++mtl) {
                    const f32x4 a = acc[mh * 4 + mtl][np * 2 + ntl];
                    uint2 uu;
                    uu.x = pk2(a[0], a[1]);
                    uu.y = pk2(a[2], a[3]);
                    *reinterpret_cast<uint2*>(&ws[(ntl * 16 + l16) * 72 + mtl * 16 + quad * 4]) = uu;
                }
            const int tb = ((int)M0 & 1023) + wm * 128 + mh * 64 + c8;
            const int hd00v = ((int)blockIdx.x - 8) * 256 + wn * 64 + np * 32;
#pragma unroll
            for (int q4 = 0; q4 < 4; ++q4) {
                const int col = q4 * 8 + colr;
                const int hd = hd00v + col;
                const int h = hd >> 6, d = hd & 63;
                short8 v = *reinterpret_cast<const short8*>(&ws[col * 72 + c8]);
                *reinterpret_cast<short8*>(&vT[(long)(b * 16 + h) * 65536 + (long)d * 1024 + tb]) = v;
            }
        }
    }
#undef STG
#undef RDALL
#undef MMALL
}

// ---------------- out-proj GEMM: 128x128, TRIPLE-buffer counted-vmcnt pipeline ----------------
// (unchanged — passed in rounds 4-8)
__global__ __launch_bounds__(256)
void gemm_out(const bf16* __restrict__ A0g, const bf16* __restrict__ B0g, float* __restrict__ C0,
              const bf16* __restrict__ A1g, const bf16* __restrict__ B1g, float* __restrict__ C1) {
    __shared__ short smem2[24576];   // 3 bufs x (A 4096 + B 4096)
    const int z = blockIdx.z;
    const short* A = reinterpret_cast<const short*>(z ? A1g : A0g);
    const short* B = reinterpret_cast<const short*>(z ? B1g : B0g);
    const int tid  = threadIdx.x;
    const int lane = tid & 63;
    const int w    = tid >> 6;
    const int wr   = w >> 1;
    const int wc   = w & 1;
    const int quad = lane >> 4;
    const int l16  = lane & 15;
    const long bM = (long)blockIdx.y * 128;

    f32x4 acc[4][4] = {};

    const int sr  = lane >> 2;
    const int scs = ((lane & 3) ^ (sr & 3)) * 8;
    const short* Ag0 = A + (bM + 32 * w + sr) * 1024 + scs;
    const short* Ag1 = Ag0 + 16 * 1024;
    const short* Bg0 = B + ((long)blockIdx.x * 128 + 32 * w + sr) * 1024 + scs;
    const short* Bg1 = Bg0 + 16 * 1024;
    const int sq = (quad ^ (l16 & 3)) * 8;

    {   // prologue: tile 0 -> buf 0
        short* sb = smem2;
        gload16(Ag0, sb + w * 1024);
        gload16(Ag1, sb + w * 1024 + 512);
        gload16(Bg0, sb + 4096 + w * 1024);
        gload16(Bg1, sb + 4096 + w * 1024 + 512);
    }

    int bcur = 0;
#pragma unroll 1
    for (int iter = 0; iter < 32; ++iter) {
        int bnext = bcur + 1; if (bnext == 3) bnext = 0;
        if (iter < 31) {
            const int koff = (iter + 1) * 32;
            short* sb = smem2 + bnext * 8192;
            gload16(Ag0 + koff, sb + w * 1024);
            gload16(Ag1 + koff, sb + w * 1024 + 512);
            gload16(Bg0 + koff, sb + 4096 + w * 1024);
            gload16(Bg1 + koff, sb + 4096 + w * 1024 + 512);
            asm volatile("s_waitcnt vmcnt(4)" ::: "memory");
        } else {
            asm volatile("s_waitcnt vmcnt(0)" ::: "memory");
        }
        __builtin_amdgcn_s_barrier();
        __builtin_amdgcn_sched_barrier(0);

        const short* Ab = smem2 + bcur * 8192;
        const short* Bb = Ab + 4096;

        short8 af[4], bfr[4];
#pragma unroll
        for (int mt = 0; mt < 4; ++mt)
            af[mt] = *reinterpret_cast<const short8*>(&Ab[(wr * 64 + mt * 16 + l16) * 32 + sq]);
#pragma unroll
        for (int nt = 0; nt < 4; ++nt)
            bfr[nt] = *reinterpret_cast<const short8*>(&Bb[(wc * 64 + nt * 16 + l16) * 32 + sq]);
        __builtin_amdgcn_s_setprio(1);
#pragma unroll
        for (int mt = 0; mt < 4; ++mt)
#pragma unroll
            for (int nt = 0; nt < 4; ++nt)
                acc[mt][nt] = MFMA_BF16(af[mt], bfr[nt], acc[mt][nt]);
        __builtin_amdgcn_s_setprio(0);
        bcur = bnext;
    }

    float* C = z ? C1 : C0;
    const long crow = bM + wr * 64 + quad * 4;
    const long ccol = (long)blockIdx.x * 128 + wc * 64 + l16;
#pragma unroll
    for (int mt = 0; mt < 4; ++mt)
#pragma unroll
        for (int nt = 0; nt < 4; ++nt)
#pragma unroll
            for (int r = 0; r < 4; ++r)
                C[(crow + mt * 16 + r) * 1024L + ccol + nt * 16] = acc[mt][nt][r];
}

// ---------------- flash attention: TRIPLE-buffer single-barrier pipeline + raw v_exp_f32 ----------------
// (unchanged — passed in rounds 4-8)
__global__ __launch_bounds__(256)
void attn_kernel(const bf16* __restrict__ q0g, const bf16* __restrict__ k0g,
                 const bf16* __restrict__ v0g, bf16* __restrict__ o0g,
                 const bf16* __restrict__ q1g, const bf16* __restrict__ k1g,
                 const bf16* __restrict__ v1g, bf16* __restrict__ o1g) {
    __shared__ short smem[24576];   // 3 bufs x (K 4096 + V 4096) shorts = 48KB
    const int bh = blockIdx.x;
    const int qt = blockIdx.y;
    const int z = blockIdx.z;
    const int b = bh >> 4, h = bh & 15;
    const int tid = threadIdx.x, lane = tid & 63, w = tid >> 6;
    const int quad = lane >> 4, l16 = lane & 15;

    const short* Qb = reinterpret_cast<const short*>(z ? q1g : q0g) + (long)bh * 1024 * 64;
    const short* Kb = reinterpret_cast<const short*>(z ? k1g : k0g) + (long)bh * 1024 * 64;
    const short* Vb = reinterpret_cast<const short*>(z ? v1g : v0g) + (long)bh * 64 * 1024;
    short* Ob = reinterpret_cast<short*>(z ? o1g : o0g);

    short8 qb[2][2];
#pragma unroll
    for (int qg = 0; qg < 2; ++qg) {
        const short* Qp = Qb + (long)(qt * 128 + qg * 64 + w * 16 + l16) * 64;
        qb[qg][0] = *reinterpret_cast<const short8*>(Qp + quad * 8);
        qb[qg][1] = *reinterpret_cast<const short8*>(Qp + 32 + quad * 8);
    }

    // staging: rows 16w+r8 (bit3=0, f=r8&3) and 16w+8+r8 (bit3=1, f=(r8&3)|4)
    const int r8  = lane >> 3;
    const int sc0 = ((lane & 7) ^ (r8 & 3)) * 8;
    const short* Kg0 = Kb + (long)(16 * w + r8) * 64 + sc0;
    const short* Kg1 = Kb + (long)(16 * w + 8 + r8) * 64 + (sc0 ^ 32);
    const short* Vg0 = Vb + (long)(16 * w + r8) * 1024 + sc0;
    const short* Vg1 = Vb + (long)(16 * w + 8 + r8) * 1024 + (sc0 ^ 32);

    const int jbase = 8 * (l16 >> 2) + (l16 & 3);
    // read-side swizzle constants (row bits expressed via l16)
    const int fKs = (l16 & 3) | (((l16 >> 2) & 1) << 2);
    const int s0  = (quad ^ fKs) * 8;
    const int fVs = (l16 & 3) | (((l16 >> 3) & 1) << 2);
    const int sv  = (quad ^ fVs) * 8;

    f32x4 o[2][4] = {};
    float li[2] = {0.f, 0.f};

    // prologue: tile 0 -> buf 0
    gload16(Kg0, smem + w * 1024); gload16(Kg1, smem + w * 1024 + 512);
    gload16(Vg0, smem + 4096 + w * 1024); gload16(Vg1, smem + 4096 + w * 1024 + 512);

    int bcur = 0;
#pragma unroll 1
    for (int iter = 0; iter < 16; ++iter) {
        int bnext = bcur + 1; if (bnext == 3) bnext = 0;
        if (iter < 15) {   // stage tile t+1 into beta(t+1)
            short* sb = smem + bnext * 8192;
            const long ko = (long)(iter + 1) * 4096;   // K: 64 t-rows * 64 shorts
            const long vo = (long)(iter + 1) * 64;     // V: within-row t offset
            gload16(Kg0 + ko, sb + w * 1024);
            gload16(Kg1 + ko, sb + w * 1024 + 512);
            gload16(Vg0 + vo, sb + 4096 + w * 1024);
            gload16(Vg1 + vo, sb + 4096 + w * 1024 + 512);
            asm volatile("s_waitcnt vmcnt(4)" ::: "memory");
        } else {
            asm volatile("s_waitcnt vmcnt(0)" ::: "memory");
        }
        __builtin_amdgcn_s_barrier();
        __builtin_amdgcn_sched_barrier(0);

        const short* Ks = smem + bcur * 8192;
        const short* Vs = Ks + 4096;

        f32x4 st[2][4];
        __builtin_amdgcn_s_setprio(1);
#pragma unroll
        for (int g = 0; g < 4; ++g) {
            const int goff = (g >> 1) * 32 + (g & 1) * 4;
            const short* kr = Ks + (jbase + goff) * 64;
            short8 k0 = *reinterpret_cast<const short8*>(kr + s0);
            short8 k1 = *reinterpret_cast<const short8*>(kr + (s0 ^ 32));
#pragma unroll
            for (int qg = 0; qg < 2; ++qg) {
                f32x4 zf = {0.f, 0.f, 0.f, 0.f};
                zf = MFMA_BF16(k0, qb[qg][0], zf);
                zf = MFMA_BF16(k1, qb[qg][1], zf);
                st[qg][g] = zf;
            }
        }
        __builtin_amdgcn_s_setprio(0);

        union { unsigned int u[4]; short8 s; } f0[2], f1[2];
#pragma unroll
        for (int qg = 0; qg < 2; ++qg) {
            float p[4][4];
            float rs = 0.f;
#pragma unroll
            for (int g = 0; g < 4; ++g)
#pragma unroll
                for (int r = 0; r < 4; ++r) {
                    float e = EXP2F(st[qg][g][r]);
                    p[g][r] = e;
                    rs += e;
                }
            li[qg] += rs;
            f0[qg].u[0] = pk2(p[0][0], p[0][1]); f0[qg].u[1] = pk2(p[0][2], p[0][3]);
            f0[qg].u[2] = pk2(p[1][0], p[1][1]); f0[qg].u[3] = pk2(p[1][2], p[1][3]);
            f1[qg].u[0] = pk2(p[2][0], p[2][1]); f1[qg].u[1] = pk2(p[2][2], p[2][3]);
            f1[qg].u[2] = pk2(p[3][0], p[3][1]); f1[qg].u[3] = pk2(p[3][2], p[3][3]);
        }

        __builtin_amdgcn_s_setprio(1);
#pragma unroll
        for (int dt = 0; dt < 4; ++dt) {
            const short* vr = Vs + (dt * 16 + l16) * 64;
            short8 v0 = *reinterpret_cast<const short8*>(vr + sv);
            short8 v1 = *reinterpret_cast<const short8*>(vr + (sv ^ 32));
#pragma unroll
            for (int qg = 0; qg < 2; ++qg) {
                o[qg][dt] = MFMA_BF16(v0, f0[qg].s, o[qg][dt]);
                o[qg][dt] = MFMA_BF16(v1, f1[qg].s, o[qg][dt]);
            }
        }
        __builtin_amdgcn_s_setprio(0);
        bcur = bnext;
    }

    __syncthreads();   // O-staging below reuses smem regions that overlap K/V bufs

#pragma unroll
    for (int qg = 0; qg < 2; ++qg) {
        li[qg] += __shfl_xor(li[qg], 16);
        li[qg] += __shfl_xor(li[qg], 32);
    }

#pragma unroll
    for (int qg = 0; qg < 2; ++qg) {
        short* Os = smem + qg * 5120 + w * 1280;
        const float rl = 1.0f / li[qg];
#pragma unroll
        for (int dt = 0; dt < 4; ++dt) {
            uint2 uu;
            uu.x = pk2(o[qg][dt][0] * rl, o[qg][dt][1] * rl);
            uu.y = pk2(o[qg][dt][2] * rl, o[qg][dt][3] * rl);
            *reinterpret_cast<uint2*>(&Os[l16 * 80 + dt * 16 + quad * 4]) = uu;
        }
#pragma unroll
        for (int p = 0; p < 2; ++p) {
            int row = p * 8 + (lane >> 3);
            int ch = (lane & 7) * 8;
            short8 v = *reinterpret_cast<const short8*>(&Os[row * 80 + ch]);
            *reinterpret_cast<short8*>(&Ob[((long)(b * 1024) + qt * 128 + qg * 64 + w * 16 + row) * 1024 + h * 64 + ch]) = v;
        }
    }
}

extern "C" void kernel_launch(void* const* d_in, const int* in_sizes, int n_in,
                              void* d_out, int out_size, void* d_ws, size_t ws_size,
                              hipStream_t stream) {
    const float* x     = (const float*)d_in[0];
    const float* y     = (const float*)d_in[1];
    const float* Wqkv1 = (const float*)d_in[2];
    const float* Wqkv2 = (const float*)d_in[3];
    const float* Wout1 = (const float*)d_in[4];
    const float* Wout2 = (const float*)d_in[5];

    char* ws = (char*)d_ws;
    bf16* Wqkv1b = (bf16*)(ws + 0);          // 6291456
    bf16* Wqkv2b = (bf16*)(ws + 6291456);    // 6291456
    bf16* Wout1b = (bf16*)(ws + 12582912);   // 2097152
    bf16* Wout2b = (bf16*)(ws + 14680064);   // 2097152
    bf16* xb     = (bf16*)(ws + 16777216);   // 8388608
    bf16* yb     = (bf16*)(ws + 25165824);   // 8388608
    bf16* q1     = (bf16*)(ws + 33554432);   // 8388608  packed [bh][t][d]
    bf16* k1     = (bf16*)(ws + 41943040);   // 8388608
    bf16* v1T    = (bf16*)(ws + 50331648);   // 8388608  [bh][d][t]
    bf16* q2     = (bf16*)(ws + 58720256);   // 8388608
    bf16* k2     = (bf16*)(ws + 67108864);   // 8388608
    bf16* v2T    = (bf16*)(ws + 75497472);   // 8388608 -> 83886080 (80 MB)
    bf16* xo     = xb;                       // xb dead after qkv GEMM
    bf16* yo     = yb;

    static bool s_attr = false;
    if (!s_attr) {
        (void)hipFuncSetAttribute(reinterpret_cast<const void*>(&gemm_qkv256),
                                  hipFuncAttributeMaxDynamicSharedMemorySize, 65536);
        s_attr = true;
    }

    // 1. all converts (x, y, Wout, Wqkv-permuted+scaled)
    cvt_fused<<<dim3(4096, 6), 256, 0, stream>>>(x, y, Wout1, Wout2, Wqkv1, Wqkv2,
                                                 xb, yb, Wout1b, Wout2b, Wqkv1b, Wqkv2b);

    // 2. qkv GEMM: 256x256 block, 128x64 wave tile, BK=32, 64KB LDS -> 2 blocks/CU
    gemm_qkv256<<<dim3(12, 16, 2), 512, 65536, stream>>>(xb, Wqkv1b, q1, k1, v1T,
                                                         yb, Wqkv2b, q2, k2, v2T);

    // 3. cross attention: z=0: softmax(q2 k1^T) v1 -> xo ; z=1: softmax(q1 k2^T) v2 -> yo
    attn_kernel<<<dim3(64, 8, 2), 256, 0, stream>>>(q2, k1, v1T, xo,
                                                    q1, k2, v2T, yo);

    // 4. output projections (triple-buffer counted-vmcnt pipeline, fp32 epilogue)
    gemm_out<<<dim3(8, 32, 2), 256, 0, stream>>>(xo, Wout1b, (float*)d_out,
                                                 yo, Wout2b, ((float*)d_out) + 4194304);
}

// Round 10
// 251.771 us; speedup vs baseline: 2.7721x; 2.7721x over previous
//
#include <hip/hip_runtime.h>
#include <hip/hip_bf16.h>

typedef __hip_bfloat16 bf16;
typedef __attribute__((ext_vector_type(8))) short short8;
typedef __attribute__((ext_vector_type(4))) short short4v;
typedef __attribute__((ext_vector_type(4))) float f32x4;

#define MFMA_BF16(a, b, c) __builtin_amdgcn_mfma_f32_16x16x32_bf16((a), (b), (c), 0, 0, 0)

// 1/sqrt(E/H) * log2(e) folded into Wqkv q-rows: softmax exps become plain exp2
#define QSCALE 0.1803368860111270f

__device__ __forceinline__ short f2bf(float f) {
    union { bf16 h; short s; } u;
    u.h = __float2bfloat16(f);
    return u.s;
}

#if defined(__has_builtin) && __has_builtin(__builtin_amdgcn_cvt_pk_bf16_f32)
typedef __attribute__((ext_vector_type(2))) __bf16 bf16x2_t;
__device__ __forceinline__ unsigned int pk2(float a, float b) {
    union { bf16x2_t v; unsigned int u; } x;
    x.v = __builtin_amdgcn_cvt_pk_bf16_f32(a, b);
    return x.u;
}
#else
__device__ __forceinline__ unsigned int pk2(float a, float b) {
    union { bf16 h[2]; unsigned int u; } x;
    x.h[0] = __float2bfloat16(a);
    x.h[1] = __float2bfloat16(b);
    return x.u;
}
#endif

// raw v_exp_f32 (skip LLVM's denormal-range fixup: scores are far from -126)
#if defined(__has_builtin) && __has_builtin(__builtin_amdgcn_exp2f)
#define EXP2F(x) __builtin_amdgcn_exp2f(x)
#else
#define EXP2F(x) exp2f(x)
#endif

// async global->LDS, 16B per lane; dest = wave-uniform base + lane*16 (linear)
__device__ __forceinline__ void gload16(const void* g, void* l) {
    __builtin_amdgcn_global_load_lds(
        (const __attribute__((address_space(1))) unsigned int*)g,
        (__attribute__((address_space(3))) unsigned int*)l, 16, 0, 0);
}

// ---------------- ALL converts in one dispatch (grid.y selects tensor / mode) ----------------
__global__ void cvt_fused(const float* __restrict__ x, const float* __restrict__ y,
                          const float* __restrict__ wo1, const float* __restrict__ wo2,
                          const float* __restrict__ wq1, const float* __restrict__ wq2,
                          bf16* __restrict__ ox, bf16* __restrict__ oy,
                          bf16* __restrict__ oo1, bf16* __restrict__ oo2,
                          bf16* __restrict__ oq1, bf16* __restrict__ oq2) {
    const int yb = blockIdx.y;
    if (yb < 4) {
        int i = blockIdx.x * 256 + threadIdx.x;
        const float* src; bf16* dst; int n4;
        switch (yb) {
            case 0:  src = x;   dst = ox;  n4 = 1048576; break;
            case 1:  src = y;   dst = oy;  n4 = 1048576; break;
            case 2:  src = wo1; dst = oo1; n4 = 262144;  break;
            default: src = wo2; dst = oo2; n4 = 262144;  break;
        }
        if (i >= n4) return;
        float4 f = reinterpret_cast<const float4*>(src)[i];
        short4v s;
        s.x = f2bf(f.x); s.y = f2bf(f.y); s.z = f2bf(f.z); s.w = f2bf(f.w);
        reinterpret_cast<short4v*>(dst)[i] = s;
    } else {
        // dest row n' = comp*1024 + h*64 + d  <-  src row d*48 + comp*16 + h
        const int np = blockIdx.x;
        if (np >= 3072) return;
        const int comp = np >> 10, rem = np & 1023, h = rem >> 6, d = rem & 63;
        const int srow = d * 48 + comp * 16 + h;
        const float* src = ((yb == 5) ? wq2 : wq1) + (long)srow * 1024;
        bf16* dst = ((yb == 5) ? oq2 : oq1) + (long)np * 1024;
        const float sc = (comp == 0) ? QSCALE : 1.0f;
        int t = threadIdx.x;
        float4 f = reinterpret_cast<const float4*>(src)[t];
        short4v s;
        s.x = f2bf(f.x * sc); s.y = f2bf(f.y * sc); s.z = f2bf(f.z * sc); s.w = f2bf(f.w * sc);
        reinterpret_cast<short4v*>(dst)[t] = s;
    }
}

// ---------------- 256x256 qkv GEMM, BK=32, 8 waves of 128x64, 2-buf stage-after-gate ----------------
// R9 post-mortem: __launch_bounds__(512,4) capped each wave at 128 unified VGPR+AGPR;
// the 128-AGPR accumulator alone filled it -> af/bfv + addressing spilled to scratch
// (2.2 GB of spill traffic, 530 us). Fix: (512,2) -> 256 regs/wave budget; true footprint
// ~128 AGPR + ~70 VGPR fits with NO spill. Occupancy: 1 block/CU (2 waves/SIMD) — R6's
// occupancy but +33% MFMA-per-LDS-byte (128x64 wave tile) and one gate per K-tile.
// Schedule unchanged from R9 (passed correctness): gate {vmcnt(0); s_barrier} -> stage
// tile t+1 (4 gloads/wave) -> read 12 frags -> 32 MFMA. Swizzle both-sides (row>>1)&3.
__global__ __launch_bounds__(512, 2)
void gemm_qkv256(const bf16* __restrict__ A0g, const bf16* __restrict__ B0g,
                 void* o0a, void* o0b, void* o0c,
                 const bf16* __restrict__ A1g, const bf16* __restrict__ B1g,
                 void* o1a, void* o1b, void* o1c) {
    extern __shared__ short smem[];   // 32768 shorts = 64KB (2 bufs x 16384)
    const int z = blockIdx.z;
    const short* A = reinterpret_cast<const short*>(z ? A1g : A0g);
    const short* B = reinterpret_cast<const short*>(z ? B1g : B0g);
    const int tid  = threadIdx.x;
    const int lane = tid & 63;
    const int w    = tid >> 6;        // 0..7
    const int quad = lane >> 4;
    const int l16  = lane & 15;
    const long M0 = (long)blockIdx.y * 256;
    const long N0 = (long)blockIdx.x * 256;

    const int wm = w >> 2;            // wave M-half (0..1), 128 rows
    const int wn = w & 3;             // wave N-group (0..3), 64 cols
    const int cA0  = (quad ^ ((l16 >> 1) & 3)) * 8;     // read slot (h = row bits 1-2)
    const int aoff = wm * 4096 + l16 * 32;              // A row base (shorts, within buf)
    const int boff = 8192 + wn * 2048 + l16 * 32;       // B row base within buf

    // staging: 4 lanes/row (4 chunks x 16B = 64B row), 16 rows per gload16;
    // wave w stages A rows 32w..32w+31 and B rows 32w..32w+31 (2 gloads each)
    const int srow = lane >> 2;                          // 0..15
    const int scs  = ((lane & 3) ^ ((srow >> 1) & 3)) * 8;  // swizzled source chunk
    const short* Asrc = A + (M0 + 32 * w + srow) * 1024 + scs;
    const short* Bsrc = B + (N0 + 32 * w + srow) * 1024 + scs;

    f32x4 acc[8][4] = {};
    short8 af[8], bfv[4];

#define STG(tt, nbase) do { \
    const short* _a = Asrc + (tt) * 32; \
    const short* _b = Bsrc + (tt) * 32; \
    short* _da = smem + (nbase) + w * 1024; \
    short* _db = _da + 8192; \
    gload16(_a, _da); gload16(_a + 16384, _da + 512); \
    gload16(_b, _db); gload16(_b + 16384, _db + 512); } while (0)
#define RDALL(bbv) do { \
    _Pragma("unroll") for (int mt = 0; mt < 8; ++mt) \
        af[mt] = *reinterpret_cast<const short8*>(&smem[(bbv) + aoff + mt * 512 + cA0]); \
    _Pragma("unroll") for (int nt = 0; nt < 4; ++nt) \
        bfv[nt] = *reinterpret_cast<const short8*>(&smem[(bbv) + boff + nt * 512 + cA0]); } while (0)
#define MMALL() do { \
    __builtin_amdgcn_s_setprio(1); \
    _Pragma("unroll") for (int mt = 0; mt < 8; ++mt) \
    _Pragma("unroll") for (int nt = 0; nt < 4; ++nt) \
        acc[mt][nt] = MFMA_BF16(af[mt], bfv[nt], acc[mt][nt]); \
    __builtin_amdgcn_s_setprio(0); } while (0)

    // prologue: tile 0 -> buf 0
    STG(0, 0);

#pragma unroll 1
    for (int t = 0; t < 32; ++t) {
        // gate: drains tile t's loads (issued a full iter earlier -> mostly hidden)
        asm volatile("s_waitcnt vmcnt(0)" ::: "memory");
        __builtin_amdgcn_s_barrier();
        __builtin_amdgcn_sched_barrier(0);
        if (t < 31) STG(t + 1, ((t + 1) & 1) << 14);
        const int bb = (t & 1) << 14;
        RDALL(bb);
        MMALL();
    }

    __syncthreads();   // epilogue ws scratch overlaps buf1 (wave 7's region)

    if (blockIdx.x < 8) {
        // q (x<4) / k (x 4..7), packed [bh][t][d]
        short* dst = reinterpret_cast<short*>(blockIdx.x < 4 ? (z ? o1a : o0a)
                                                             : (z ? o1b : o0b));
        const int b = (int)(M0 >> 10);
        const int t00 = ((int)M0 & 1023) + wm * 128 + quad * 4;
        const int hd00 = ((int)blockIdx.x & 3) * 256 + wn * 64;
#pragma unroll
        for (int nt = 0; nt < 4; ++nt) {
            const int hd = hd00 + nt * 16 + l16;
            const int h = hd >> 6, d = hd & 63;
            short* dp = dst + (long)(b * 16 + h) * 65536 + d;
#pragma unroll
            for (int mt = 0; mt < 8; ++mt)
#pragma unroll
                for (int r = 0; r < 4; ++r)
                    dp[(long)(t00 + mt * 16 + r) * 64] = f2bf(acc[mt][nt][r]);
        }
    } else {
        // V: per-wave LDS transpose -> vT [bh][d][t]; 4 passes of 64t x 32hd
        short* vT = reinterpret_cast<short*>(z ? o1c : o0c);
        const int b = (int)(M0 >> 10);
        short* ws = smem + w * 2304;     // 32 cols x 72 shorts, wave-private
        const int c8 = (lane & 7) * 8;
        const int colr = lane >> 3;
#pragma unroll
        for (int ph = 0; ph < 4; ++ph) {
            const int mh = ph >> 1, np = ph & 1;
#pragma unroll
            for (int ntl = 0; ntl < 2; ++ntl)
#pragma unroll
                for (int mtl = 0; mtl < 4; ++mtl) {
                    const f32x4 a = acc[mh * 4 + mtl][np * 2 + ntl];
                    uint2 uu;
                    uu.x = pk2(a[0], a[1]);
                    uu.y = pk2(a[2], a[3]);
                    *reinterpret_cast<uint2*>(&ws[(ntl * 16 + l16) * 72 + mtl * 16 + quad * 4]) = uu;
                }
            const int tb = ((int)M0 & 1023) + wm * 128 + mh * 64 + c8;
            const int hd00v = ((int)blockIdx.x - 8) * 256 + wn * 64 + np * 32;
#pragma unroll
            for (int q4 = 0; q4 < 4; ++q4) {
                const int col = q4 * 8 + colr;
                const int hd = hd00v + col;
                const int h = hd >> 6, d = hd & 63;
                short8 v = *reinterpret_cast<const short8*>(&ws[col * 72 + c8]);
                *reinterpret_cast<short8*>(&vT[(long)(b * 16 + h) * 65536 + (long)d * 1024 + tb]) = v;
            }
        }
    }
#undef STG
#undef RDALL
#undef MMALL
}

// ---------------- out-proj GEMM: 128x128, TRIPLE-buffer counted-vmcnt pipeline ----------------
// (unchanged — passed in rounds 4-9)
__global__ __launch_bounds__(256)
void gemm_out(const bf16* __restrict__ A0g, const bf16* __restrict__ B0g, float* __restrict__ C0,
              const bf16* __restrict__ A1g, const bf16* __restrict__ B1g, float* __restrict__ C1) {
    __shared__ short smem2[24576];   // 3 bufs x (A 4096 + B 4096)
    const int z = blockIdx.z;
    const short* A = reinterpret_cast<const short*>(z ? A1g : A0g);
    const short* B = reinterpret_cast<const short*>(z ? B1g : B0g);
    const int tid  = threadIdx.x;
    const int lane = tid & 63;
    const int w    = tid >> 6;
    const int wr   = w >> 1;
    const int wc   = w & 1;
    const int quad = lane >> 4;
    const int l16  = lane & 15;
    const long bM = (long)blockIdx.y * 128;

    f32x4 acc[4][4] = {};

    const int sr  = lane >> 2;
    const int scs = ((lane & 3) ^ (sr & 3)) * 8;
    const short* Ag0 = A + (bM + 32 * w + sr) * 1024 + scs;
    const short* Ag1 = Ag0 + 16 * 1024;
    const short* Bg0 = B + ((long)blockIdx.x * 128 + 32 * w + sr) * 1024 + scs;
    const short* Bg1 = Bg0 + 16 * 1024;
    const int sq = (quad ^ (l16 & 3)) * 8;

    {   // prologue: tile 0 -> buf 0
        short* sb = smem2;
        gload16(Ag0, sb + w * 1024);
        gload16(Ag1, sb + w * 1024 + 512);
        gload16(Bg0, sb + 4096 + w * 1024);
        gload16(Bg1, sb + 4096 + w * 1024 + 512);
    }

    int bcur = 0;
#pragma unroll 1
    for (int iter = 0; iter < 32; ++iter) {
        int bnext = bcur + 1; if (bnext == 3) bnext = 0;
        if (iter < 31) {
            const int koff = (iter + 1) * 32;
            short* sb = smem2 + bnext * 8192;
            gload16(Ag0 + koff, sb + w * 1024);
            gload16(Ag1 + koff, sb + w * 1024 + 512);
            gload16(Bg0 + koff, sb + 4096 + w * 1024);
            gload16(Bg1 + koff, sb + 4096 + w * 1024 + 512);
            asm volatile("s_waitcnt vmcnt(4)" ::: "memory");
        } else {
            asm volatile("s_waitcnt vmcnt(0)" ::: "memory");
        }
        __builtin_amdgcn_s_barrier();
        __builtin_amdgcn_sched_barrier(0);

        const short* Ab = smem2 + bcur * 8192;
        const short* Bb = Ab + 4096;

        short8 af[4], bfr[4];
#pragma unroll
        for (int mt = 0; mt < 4; ++mt)
            af[mt] = *reinterpret_cast<const short8*>(&Ab[(wr * 64 + mt * 16 + l16) * 32 + sq]);
#pragma unroll
        for (int nt = 0; nt < 4; ++nt)
            bfr[nt] = *reinterpret_cast<const short8*>(&Bb[(wc * 64 + nt * 16 + l16) * 32 + sq]);
        __builtin_amdgcn_s_setprio(1);
#pragma unroll
        for (int mt = 0; mt < 4; ++mt)
#pragma unroll
            for (int nt = 0; nt < 4; ++nt)
                acc[mt][nt] = MFMA_BF16(af[mt], bfr[nt], acc[mt][nt]);
        __builtin_amdgcn_s_setprio(0);
        bcur = bnext;
    }

    float* C = z ? C1 : C0;
    const long crow = bM + wr * 64 + quad * 4;
    const long ccol = (long)blockIdx.x * 128 + wc * 64 + l16;
#pragma unroll
    for (int mt = 0; mt < 4; ++mt)
#pragma unroll
        for (int nt = 0; nt < 4; ++nt)
#pragma unroll
            for (int r = 0; r < 4; ++r)
                C[(crow + mt * 16 + r) * 1024L + ccol + nt * 16] = acc[mt][nt][r];
}

// ---------------- flash attention: TRIPLE-buffer single-barrier pipeline + raw v_exp_f32 ----------------
// (unchanged — passed in rounds 4-9)
__global__ __launch_bounds__(256)
void attn_kernel(const bf16* __restrict__ q0g, const bf16* __restrict__ k0g,
                 const bf16* __restrict__ v0g, bf16* __restrict__ o0g,
                 const bf16* __restrict__ q1g, const bf16* __restrict__ k1g,
                 const bf16* __restrict__ v1g, bf16* __restrict__ o1g) {
    __shared__ short smem[24576];   // 3 bufs x (K 4096 + V 4096) shorts = 48KB
    const int bh = blockIdx.x;
    const int qt = blockIdx.y;
    const int z = blockIdx.z;
    const int b = bh >> 4, h = bh & 15;
    const int tid = threadIdx.x, lane = tid & 63, w = tid >> 6;
    const int quad = lane >> 4, l16 = lane & 15;

    const short* Qb = reinterpret_cast<const short*>(z ? q1g : q0g) + (long)bh * 1024 * 64;
    const short* Kb = reinterpret_cast<const short*>(z ? k1g : k0g) + (long)bh * 1024 * 64;
    const short* Vb = reinterpret_cast<const short*>(z ? v1g : v0g) + (long)bh * 64 * 1024;
    short* Ob = reinterpret_cast<short*>(z ? o1g : o0g);

    short8 qb[2][2];
#pragma unroll
    for (int qg = 0; qg < 2; ++qg) {
        const short* Qp = Qb + (long)(qt * 128 + qg * 64 + w * 16 + l16) * 64;
        qb[qg][0] = *reinterpret_cast<const short8*>(Qp + quad * 8);
        qb[qg][1] = *reinterpret_cast<const short8*>(Qp + 32 + quad * 8);
    }

    // staging: rows 16w+r8 (bit3=0, f=r8&3) and 16w+8+r8 (bit3=1, f=(r8&3)|4)
    const int r8  = lane >> 3;
    const int sc0 = ((lane & 7) ^ (r8 & 3)) * 8;
    const short* Kg0 = Kb + (long)(16 * w + r8) * 64 + sc0;
    const short* Kg1 = Kb + (long)(16 * w + 8 + r8) * 64 + (sc0 ^ 32);
    const short* Vg0 = Vb + (long)(16 * w + r8) * 1024 + sc0;
    const short* Vg1 = Vb + (long)(16 * w + 8 + r8) * 1024 + (sc0 ^ 32);

    const int jbase = 8 * (l16 >> 2) + (l16 & 3);
    // read-side swizzle constants (row bits expressed via l16)
    const int fKs = (l16 & 3) | (((l16 >> 2) & 1) << 2);
    const int s0  = (quad ^ fKs) * 8;
    const int fVs = (l16 & 3) | (((l16 >> 3) & 1) << 2);
    const int sv  = (quad ^ fVs) * 8;

    f32x4 o[2][4] = {};
    float li[2] = {0.f, 0.f};

    // prologue: tile 0 -> buf 0
    gload16(Kg0, smem + w * 1024); gload16(Kg1, smem + w * 1024 + 512);
    gload16(Vg0, smem + 4096 + w * 1024); gload16(Vg1, smem + 4096 + w * 1024 + 512);

    int bcur = 0;
#pragma unroll 1
    for (int iter = 0; iter < 16; ++iter) {
        int bnext = bcur + 1; if (bnext == 3) bnext = 0;
        if (iter < 15) {   // stage tile t+1 into beta(t+1)
            short* sb = smem + bnext * 8192;
            const long ko = (long)(iter + 1) * 4096;   // K: 64 t-rows * 64 shorts
            const long vo = (long)(iter + 1) * 64;     // V: within-row t offset
            gload16(Kg0 + ko, sb + w * 1024);
            gload16(Kg1 + ko, sb + w * 1024 + 512);
            gload16(Vg0 + vo, sb + 4096 + w * 1024);
            gload16(Vg1 + vo, sb + 4096 + w * 1024 + 512);
            asm volatile("s_waitcnt vmcnt(4)" ::: "memory");
        } else {
            asm volatile("s_waitcnt vmcnt(0)" ::: "memory");
        }
        __builtin_amdgcn_s_barrier();
        __builtin_amdgcn_sched_barrier(0);

        const short* Ks = smem + bcur * 8192;
        const short* Vs = Ks + 4096;

        f32x4 st[2][4];
        __builtin_amdgcn_s_setprio(1);
#pragma unroll
        for (int g = 0; g < 4; ++g) {
            const int goff = (g >> 1) * 32 + (g & 1) * 4;
            const short* kr = Ks + (jbase + goff) * 64;
            short8 k0 = *reinterpret_cast<const short8*>(kr + s0);
            short8 k1 = *reinterpret_cast<const short8*>(kr + (s0 ^ 32));
#pragma unroll
            for (int qg = 0; qg < 2; ++qg) {
                f32x4 zf = {0.f, 0.f, 0.f, 0.f};
                zf = MFMA_BF16(k0, qb[qg][0], zf);
                zf = MFMA_BF16(k1, qb[qg][1], zf);
                st[qg][g] = zf;
            }
        }
        __builtin_amdgcn_s_setprio(0);

        union { unsigned int u[4]; short8 s; } f0[2], f1[2];
#pragma unroll
        for (int qg = 0; qg < 2; ++qg) {
            float p[4][4];
            float rs = 0.f;
#pragma unroll
            for (int g = 0; g < 4; ++g)
#pragma unroll
                for (int r = 0; r < 4; ++r) {
                    float e = EXP2F(st[qg][g][r]);
                    p[g][r] = e;
                    rs += e;
                }
            li[qg] += rs;
            f0[qg].u[0] = pk2(p[0][0], p[0][1]); f0[qg].u[1] = pk2(p[0][2], p[0][3]);
            f0[qg].u[2] = pk2(p[1][0], p[1][1]); f0[qg].u[3] = pk2(p[1][2], p[1][3]);
            f1[qg].u[0] = pk2(p[2][0], p[2][1]); f1[qg].u[1] = pk2(p[2][2], p[2][3]);
            f1[qg].u[2] = pk2(p[3][0], p[3][1]); f1[qg].u[3] = pk2(p[3][2], p[3][3]);
        }

        __builtin_amdgcn_s_setprio(1);
#pragma unroll
        for (int dt = 0; dt < 4; ++dt) {
            const short* vr = Vs + (dt * 16 + l16) * 64;
            short8 v0 = *reinterpret_cast<const short8*>(vr + sv);
            short8 v1 = *reinterpret_cast<const short8*>(vr + (sv ^ 32));
#pragma unroll
            for (int qg = 0; qg < 2; ++qg) {
                o[qg][dt] = MFMA_BF16(v0, f0[qg].s, o[qg][dt]);
                o[qg][dt] = MFMA_BF16(v1, f1[qg].s, o[qg][dt]);
            }
        }
        __builtin_amdgcn_s_setprio(0);
        bcur = bnext;
    }

    __syncthreads();   // O-staging below reuses smem regions that overlap K/V bufs

#pragma unroll
    for (int qg = 0; qg < 2; ++qg) {
        li[qg] += __shfl_xor(li[qg], 16);
        li[qg] += __shfl_xor(li[qg], 32);
    }

#pragma unroll
    for (int qg = 0; qg < 2; ++qg) {
        short* Os = smem + qg * 5120 + w * 1280;
        const float rl = 1.0f / li[qg];
#pragma unroll
        for (int dt = 0; dt < 4; ++dt) {
            uint2 uu;
            uu.x = pk2(o[qg][dt][0] * rl, o[qg][dt][1] * rl);
            uu.y = pk2(o[qg][dt][2] * rl, o[qg][dt][3] * rl);
            *reinterpret_cast<uint2*>(&Os[l16 * 80 + dt * 16 + quad * 4]) = uu;
        }
#pragma unroll
        for (int p = 0; p < 2; ++p) {
            int row = p * 8 + (lane >> 3);
            int ch = (lane & 7) * 8;
            short8 v = *reinterpret_cast<const short8*>(&Os[row * 80 + ch]);
            *reinterpret_cast<short8*>(&Ob[((long)(b * 1024) + qt * 128 + qg * 64 + w * 16 + row) * 1024 + h * 64 + ch]) = v;
        }
    }
}

extern "C" void kernel_launch(void* const* d_in, const int* in_sizes, int n_in,
                              void* d_out, int out_size, void* d_ws, size_t ws_size,
                              hipStream_t stream) {
    const float* x     = (const float*)d_in[0];
    const float* y     = (const float*)d_in[1];
    const float* Wqkv1 = (const float*)d_in[2];
    const float* Wqkv2 = (const float*)d_in[3];
    const float* Wout1 = (const float*)d_in[4];
    const float* Wout2 = (const float*)d_in[5];

    char* ws = (char*)d_ws;
    bf16* Wqkv1b = (bf16*)(ws + 0);          // 6291456
    bf16* Wqkv2b = (bf16*)(ws + 6291456);    // 6291456
    bf16* Wout1b = (bf16*)(ws + 12582912);   // 2097152
    bf16* Wout2b = (bf16*)(ws + 14680064);   // 2097152
    bf16* xb     = (bf16*)(ws + 16777216);   // 8388608
    bf16* yb     = (bf16*)(ws + 25165824);   // 8388608
    bf16* q1     = (bf16*)(ws + 33554432);   // 8388608  packed [bh][t][d]
    bf16* k1     = (bf16*)(ws + 41943040);   // 8388608
    bf16* v1T    = (bf16*)(ws + 50331648);   // 8388608  [bh][d][t]
    bf16* q2     = (bf16*)(ws + 58720256);   // 8388608
    bf16* k2     = (bf16*)(ws + 67108864);   // 8388608
    bf16* v2T    = (bf16*)(ws + 75497472);   // 8388608 -> 83886080 (80 MB)
    bf16* xo     = xb;                       // xb dead after qkv GEMM
    bf16* yo     = yb;

    static bool s_attr = false;
    if (!s_attr) {
        (void)hipFuncSetAttribute(reinterpret_cast<const void*>(&gemm_qkv256),
                                  hipFuncAttributeMaxDynamicSharedMemorySize, 65536);
        s_attr = true;
    }

    // 1. all converts (x, y, Wout, Wqkv-permuted+scaled)
    cvt_fused<<<dim3(4096, 6), 256, 0, stream>>>(x, y, Wout1, Wout2, Wqkv1, Wqkv2,
                                                 xb, yb, Wout1b, Wout2b, Wqkv1b, Wqkv2b);

    // 2. qkv GEMM: 256x256 block, 128x64 wave tile, BK=32, 64KB LDS, no-spill reg budget
    gemm_qkv256<<<dim3(12, 16, 2), 512, 65536, stream>>>(xb, Wqkv1b, q1, k1, v1T,
                                                         yb, Wqkv2b, q2, k2, v2T);

    // 3. cross attention: z=0: softmax(q2 k1^T) v1 -> xo ; z=1: softmax(q1 k2^T) v2 -> yo
    attn_kernel<<<dim3(64, 8, 2), 256, 0, stream>>>(q2, k1, v1T, xo,
                                                    q1, k2, v2T, yo);

    // 4. output projections (triple-buffer counted-vmcnt pipeline, fp32 epilogue)
    gemm_out<<<dim3(8, 32, 2), 256, 0, stream>>>(xo, Wout1b, (float*)d_out,
                                                 yo, Wout2b, ((float*)d_out) + 4194304);
}

// Round 11
// 241.300 us; speedup vs baseline: 2.8923x; 1.0434x over previous
//
#include <hip/hip_runtime.h>
#include <hip/hip_bf16.h>

typedef __hip_bfloat16 bf16;
typedef __attribute__((ext_vector_type(8))) short short8;
typedef __attribute__((ext_vector_type(4))) short short4v;
typedef __attribute__((ext_vector_type(4))) float f32x4;

#define MFMA_BF16(a, b, c) __builtin_amdgcn_mfma_f32_16x16x32_bf16((a), (b), (c), 0, 0, 0)

// 1/sqrt(E/H) * log2(e) folded into Wqkv q-rows: softmax exps become plain exp2
#define QSCALE 0.1803368860111270f

__device__ __forceinline__ short f2bf(float f) {
    union { bf16 h; short s; } u;
    u.h = __float2bfloat16(f);
    return u.s;
}

#if defined(__has_builtin) && __has_builtin(__builtin_amdgcn_cvt_pk_bf16_f32)
typedef __attribute__((ext_vector_type(2))) __bf16 bf16x2_t;
__device__ __forceinline__ unsigned int pk2(float a, float b) {
    union { bf16x2_t v; unsigned int u; } x;
    x.v = __builtin_amdgcn_cvt_pk_bf16_f32(a, b);
    return x.u;
}
#else
__device__ __forceinline__ unsigned int pk2(float a, float b) {
    union { bf16 h[2]; unsigned int u; } x;
    x.h[0] = __float2bfloat16(a);
    x.h[1] = __float2bfloat16(b);
    return x.u;
}
#endif

// raw v_exp_f32 (skip LLVM's denormal-range fixup: scores are far from -126)
#if defined(__has_builtin) && __has_builtin(__builtin_amdgcn_exp2f)
#define EXP2F(x) __builtin_amdgcn_exp2f(x)
#else
#define EXP2F(x) exp2f(x)
#endif

// async global->LDS, 16B per lane; dest = wave-uniform base + lane*16 (linear)
__device__ __forceinline__ void gload16(const void* g, void* l) {
    __builtin_amdgcn_global_load_lds(
        (const __attribute__((address_space(1))) unsigned int*)g,
        (__attribute__((address_space(3))) unsigned int*)l, 16, 0, 0);
}

// ---------------- ALL converts in one dispatch (grid.y selects tensor / mode) ----------------
__global__ void cvt_fused(const float* __restrict__ x, const float* __restrict__ y,
                          const float* __restrict__ wo1, const float* __restrict__ wo2,
                          const float* __restrict__ wq1, const float* __restrict__ wq2,
                          bf16* __restrict__ ox, bf16* __restrict__ oy,
                          bf16* __restrict__ oo1, bf16* __restrict__ oo2,
                          bf16* __restrict__ oq1, bf16* __restrict__ oq2) {
    const int yb = blockIdx.y;
    if (yb < 4) {
        int i = blockIdx.x * 256 + threadIdx.x;
        const float* src; bf16* dst; int n4;
        switch (yb) {
            case 0:  src = x;   dst = ox;  n4 = 1048576; break;
            case 1:  src = y;   dst = oy;  n4 = 1048576; break;
            case 2:  src = wo1; dst = oo1; n4 = 262144;  break;
            default: src = wo2; dst = oo2; n4 = 262144;  break;
        }
        if (i >= n4) return;
        float4 f = reinterpret_cast<const float4*>(src)[i];
        short4v s;
        s.x = f2bf(f.x); s.y = f2bf(f.y); s.z = f2bf(f.z); s.w = f2bf(f.w);
        reinterpret_cast<short4v*>(dst)[i] = s;
    } else {
        // dest row n' = comp*1024 + h*64 + d  <-  src row d*48 + comp*16 + h
        const int np = blockIdx.x;
        if (np >= 3072) return;
        const int comp = np >> 10, rem = np & 1023, h = rem >> 6, d = rem & 63;
        const int srow = d * 48 + comp * 16 + h;
        const float* src = ((yb == 5) ? wq2 : wq1) + (long)srow * 1024;
        bf16* dst = ((yb == 5) ? oq2 : oq1) + (long)np * 1024;
        const float sc = (comp == 0) ? QSCALE : 1.0f;
        int t = threadIdx.x;
        float4 f = reinterpret_cast<const float4*>(src)[t];
        short4v s;
        s.x = f2bf(f.x * sc); s.y = f2bf(f.y * sc); s.z = f2bf(f.z * sc); s.w = f2bf(f.w * sc);
        reinterpret_cast<short4v*>(dst)[t] = s;
    }
}

// ---------------- 128x256 qkv GEMM, BK=64, 8 waves, TRIPLE-buffer single-gate pipeline ----------------
// SESSION-BEST configuration (round 6: qkv 60.7 us, total 234.5). Restored exactly after the
// 128x64-wave-tile branch (rounds 9/10) regressed twice (reg-file spill / occupancy loss).
// Grid 12x32x2 = 768 blocks = 3 exact CU-rounds. LDS 144KB: 3 bufs x {A[128][64] + B[256][64]}
// shorts, linear; source chunk pre-swizzled c^(row&7), reads XOR the same -> conflict-free.
// Per iter (tile t): stage ALL of t+1 (6 loads/wave) into beta(t+1)=beta(t-2) -> vmcnt(6)
// (drains tile t, issued a FULL iter earlier -> latency hidden; no partial mid-iter drains)
// -> ONE s_barrier -> 32 MFMA. Race-free: beta(t+1)'s readers ran in compute(t-2), which all
// waves finished before barrier(t-1), which the staging wave has provably passed.
// Epilogue: x<4 -> q packed [bh][t][d], 4..7 -> k packed, 8..11 -> LDS-transpose V -> [bh][d][t].
__global__ __launch_bounds__(512, 2)
void gemm_qkv128(const bf16* __restrict__ A0g, const bf16* __restrict__ B0g,
                 void* o0a, void* o0b, void* o0c,
                 const bf16* __restrict__ A1g, const bf16* __restrict__ B1g,
                 void* o1a, void* o1b, void* o1c) {
    extern __shared__ short smem[];   // 73728 shorts = 144KB (3 bufs x 24576)
    const int z = blockIdx.z;
    const short* A = reinterpret_cast<const short*>(z ? A1g : A0g);
    const short* B = reinterpret_cast<const short*>(z ? B1g : B0g);
    const int tid  = threadIdx.x;
    const int lane = tid & 63;
    const int w    = tid >> 6;        // 0..7
    const int quad = lane >> 4;
    const int l16  = lane & 15;
    const long M0 = (long)blockIdx.y * 128;
    const long N0 = (long)blockIdx.x * 256;

    const int wm = w >> 2;            // wave M-group (0..1), 64 rows each
    const int wn = w & 3;             // wave N-group (0..3), 32 cols per B-half
    const int cA0  = (quad ^ (l16 & 7)) * 8;            // kk=0 chunk (shorts); kk=1 -> ^32
    const int aoff = wm * 4096 + l16 * 64;              // A row base (shorts, within buf)
    const int boff = 8192 + wn * 2048 + l16 * 64;       // B row base within buf
    const int w512 = w * 512;

    const short* Asrc = A + (M0 + w * 8 + (lane >> 3)) * 1024 + ((lane & 7) ^ (lane >> 3)) * 8;
    const short* Bsrc = B + (N0 + w * 8 + (lane >> 3)) * 1024 + ((lane & 7) ^ (lane >> 3)) * 8;

    f32x4 acc[2][4][2] = {};
    short8 af[4][2], bfv[2][2];

#define SA128(tt, nbase) do { \
    const short* _s = Asrc + (tt) * 64; \
    short* _d = smem + (nbase) + w512; \
    gload16(_s, _d); gload16(_s + 65536, _d + 4096); } while (0)
#define SB128(half, tt, nbase) do { \
    const short* _s = Bsrc + (half) * 131072 + (tt) * 64; \
    short* _d = smem + (nbase) + 8192 + (half) * 8192 + w512; \
    gload16(_s, _d); gload16(_s + 65536, _d + 4096); } while (0)
#define RDA128(bbv) do { \
    _Pragma("unroll") for (int mt = 0; mt < 4; ++mt) { \
        const short* _p = &smem[(bbv) + aoff + mt * 1024]; \
        af[mt][0] = *reinterpret_cast<const short8*>(_p + cA0); \
        af[mt][1] = *reinterpret_cast<const short8*>(_p + (cA0 ^ 32)); } } while (0)
#define RDB128(Bh, bbv) do { \
    _Pragma("unroll") for (int nt = 0; nt < 2; ++nt) { \
        const short* _p = &smem[(bbv) + (Bh) * 8192 + boff + nt * 1024]; \
        bfv[nt][0] = *reinterpret_cast<const short8*>(_p + cA0); \
        bfv[nt][1] = *reinterpret_cast<const short8*>(_p + (cA0 ^ 32)); } } while (0)
#define MM128(p) do { \
    __builtin_amdgcn_s_setprio(1); \
    _Pragma("unroll") for (int mt = 0; mt < 4; ++mt) \
    _Pragma("unroll") for (int nt = 0; nt < 2; ++nt) { \
        acc[p][mt][nt] = MFMA_BF16(af[mt][0], bfv[nt][0], acc[p][mt][nt]); \
        acc[p][mt][nt] = MFMA_BF16(af[mt][1], bfv[nt][1], acc[p][mt][nt]); } \
    __builtin_amdgcn_s_setprio(0); } while (0)

    // prologue: K-tile 0 fully staged into buf0 (6 loads/wave: A, B0, B1)
    SA128(0, 0); SB128(0, 0, 0); SB128(1, 0, 0);

    int bcur = 0;
#pragma unroll 1
    for (int t = 0; t < 16; ++t) {
        int bnext = bcur + 1; if (bnext == 3) bnext = 0;
        if (t < 15) {
            const int nb = bnext * 24576;
            SA128(t + 1, nb); SB128(0, t + 1, nb); SB128(1, t + 1, nb);
            asm volatile("s_waitcnt vmcnt(6)" ::: "memory");
        } else {
            asm volatile("s_waitcnt vmcnt(0)" ::: "memory");
        }
        __builtin_amdgcn_s_barrier();
        __builtin_amdgcn_sched_barrier(0);

        const int bb = bcur * 24576;
        RDA128(bb);
        RDB128(0, bb);
        MM128(0);
        RDB128(1, bb);
        MM128(1);
        bcur = bnext;
    }

    __syncthreads();   // epilogue ws scratch overlaps the tail compute buffer

    if (blockIdx.x < 8) {
        // q (x<4) / k (x 4..7), packed [bh][t][d]
        short* dst = reinterpret_cast<short*>(blockIdx.x < 4 ? (z ? o1a : o0a)
                                                             : (z ? o1b : o0b));
        const int b = (int)(M0 >> 10);
        const int t00 = ((int)M0 & 1023) + wm * 64 + quad * 4;
        const int hd00 = ((int)blockIdx.x & 3) * 256 + wn * 32;
#pragma unroll
        for (int Bh = 0; Bh < 2; ++Bh)
#pragma unroll
            for (int nt = 0; nt < 2; ++nt) {
                const int hd = hd00 + Bh * 128 + nt * 16 + l16;
                const int h = hd >> 6, d = hd & 63;
                short* dp = dst + (long)(b * 16 + h) * 65536 + d;
#pragma unroll
                for (int mt = 0; mt < 4; ++mt)
#pragma unroll
                    for (int r = 0; r < 4; ++r)
                        dp[(long)(t00 + mt * 16 + r) * 64] = f2bf(acc[Bh][mt][nt][r]);
            }
    } else {
        // V: per-wave LDS transpose -> vT [bh][d][t], coalesced 16B stores
        short* vT = reinterpret_cast<short*>(z ? o1c : o0c);
        const int b = (int)(M0 >> 10);
        const int hd00 = ((int)blockIdx.x - 8) * 256 + wn * 32;
        short* ws = smem + w * 2304;     // 32 cols x 72 shorts, wave-private
        const int c8 = (lane & 7) * 8;
        const int colr = lane >> 3;
        const int tb = ((int)M0 & 1023) + wm * 64 + c8;
#pragma unroll
        for (int Bh = 0; Bh < 2; ++Bh) {
#pragma unroll
            for (int nt = 0; nt < 2; ++nt)
#pragma unroll
                for (int mt = 0; mt < 4; ++mt) {
                    uint2 uu;
                    uu.x = pk2(acc[Bh][mt][nt][0], acc[Bh][mt][nt][1]);
                    uu.y = pk2(acc[Bh][mt][nt][2], acc[Bh][mt][nt][3]);
                    *reinterpret_cast<uint2*>(&ws[(nt * 16 + l16) * 72 + mt * 16 + quad * 4]) = uu;
                }
#pragma unroll
            for (int q4 = 0; q4 < 4; ++q4) {
                const int col = q4 * 8 + colr;
                const int hd = hd00 + Bh * 128 + col;
                const int h = hd >> 6, d = hd & 63;
                short8 v = *reinterpret_cast<const short8*>(&ws[col * 72 + c8]);
                *reinterpret_cast<short8*>(&vT[(long)(b * 16 + h) * 65536 + (long)d * 1024 + tb]) = v;
            }
        }
    }
#undef SA128
#undef SB128
#undef RDA128
#undef RDB128
#undef MM128
}

// ---------------- out-proj GEMM: 128x128, TRIPLE-buffer counted-vmcnt pipeline ----------------
// (unchanged — passed in rounds 4-10)
__global__ __launch_bounds__(256)
void gemm_out(const bf16* __restrict__ A0g, const bf16* __restrict__ B0g, float* __restrict__ C0,
              const bf16* __restrict__ A1g, const bf16* __restrict__ B1g, float* __restrict__ C1) {
    __shared__ short smem2[24576];   // 3 bufs x (A 4096 + B 4096)
    const int z = blockIdx.z;
    const short* A = reinterpret_cast<const short*>(z ? A1g : A0g);
    const short* B = reinterpret_cast<const short*>(z ? B1g : B0g);
    const int tid  = threadIdx.x;
    const int lane = tid & 63;
    const int w    = tid >> 6;
    const int wr   = w >> 1;
    const int wc   = w & 1;
    const int quad = lane >> 4;
    const int l16  = lane & 15;
    const long bM = (long)blockIdx.y * 128;

    f32x4 acc[4][4] = {};

    const int sr  = lane >> 2;
    const int scs = ((lane & 3) ^ (sr & 3)) * 8;
    const short* Ag0 = A + (bM + 32 * w + sr) * 1024 + scs;
    const short* Ag1 = Ag0 + 16 * 1024;
    const short* Bg0 = B + ((long)blockIdx.x * 128 + 32 * w + sr) * 1024 + scs;
    const short* Bg1 = Bg0 + 16 * 1024;
    const int sq = (quad ^ (l16 & 3)) * 8;

    {   // prologue: tile 0 -> buf 0
        short* sb = smem2;
        gload16(Ag0, sb + w * 1024);
        gload16(Ag1, sb + w * 1024 + 512);
        gload16(Bg0, sb + 4096 + w * 1024);
        gload16(Bg1, sb + 4096 + w * 1024 + 512);
    }

    int bcur = 0;
#pragma unroll 1
    for (int iter = 0; iter < 32; ++iter) {
        int bnext = bcur + 1; if (bnext == 3) bnext = 0;
        if (iter < 31) {
            const int koff = (iter + 1) * 32;
            short* sb = smem2 + bnext * 8192;
            gload16(Ag0 + koff, sb + w * 1024);
            gload16(Ag1 + koff, sb + w * 1024 + 512);
            gload16(Bg0 + koff, sb + 4096 + w * 1024);
            gload16(Bg1 + koff, sb + 4096 + w * 1024 + 512);
            asm volatile("s_waitcnt vmcnt(4)" ::: "memory");
        } else {
            asm volatile("s_waitcnt vmcnt(0)" ::: "memory");
        }
        __builtin_amdgcn_s_barrier();
        __builtin_amdgcn_sched_barrier(0);

        const short* Ab = smem2 + bcur * 8192;
        const short* Bb = Ab + 4096;

        short8 af[4], bfr[4];
#pragma unroll
        for (int mt = 0; mt < 4; ++mt)
            af[mt] = *reinterpret_cast<const short8*>(&Ab[(wr * 64 + mt * 16 + l16) * 32 + sq]);
#pragma unroll
        for (int nt = 0; nt < 4; ++nt)
            bfr[nt] = *reinterpret_cast<const short8*>(&Bb[(wc * 64 + nt * 16 + l16) * 32 + sq]);
        __builtin_amdgcn_s_setprio(1);
#pragma unroll
        for (int mt = 0; mt < 4; ++mt)
#pragma unroll
            for (int nt = 0; nt < 4; ++nt)
                acc[mt][nt] = MFMA_BF16(af[mt], bfr[nt], acc[mt][nt]);
        __builtin_amdgcn_s_setprio(0);
        bcur = bnext;
    }

    float* C = z ? C1 : C0;
    const long crow = bM + wr * 64 + quad * 4;
    const long ccol = (long)blockIdx.x * 128 + wc * 64 + l16;
#pragma unroll
    for (int mt = 0; mt < 4; ++mt)
#pragma unroll
        for (int nt = 0; nt < 4; ++nt)
#pragma unroll
            for (int r = 0; r < 4; ++r)
                C[(crow + mt * 16 + r) * 1024L + ccol + nt * 16] = acc[mt][nt][r];
}

// ---------------- flash attention: TRIPLE-buffer single-barrier pipeline + raw v_exp_f32 ----------------
// (unchanged — passed in rounds 4-10)
__global__ __launch_bounds__(256)
void attn_kernel(const bf16* __restrict__ q0g, const bf16* __restrict__ k0g,
                 const bf16* __restrict__ v0g, bf16* __restrict__ o0g,
                 const bf16* __restrict__ q1g, const bf16* __restrict__ k1g,
                 const bf16* __restrict__ v1g, bf16* __restrict__ o1g) {
    __shared__ short smem[24576];   // 3 bufs x (K 4096 + V 4096) shorts = 48KB
    const int bh = blockIdx.x;
    const int qt = blockIdx.y;
    const int z = blockIdx.z;
    const int b = bh >> 4, h = bh & 15;
    const int tid = threadIdx.x, lane = tid & 63, w = tid >> 6;
    const int quad = lane >> 4, l16 = lane & 15;

    const short* Qb = reinterpret_cast<const short*>(z ? q1g : q0g) + (long)bh * 1024 * 64;
    const short* Kb = reinterpret_cast<const short*>(z ? k1g : k0g) + (long)bh * 1024 * 64;
    const short* Vb = reinterpret_cast<const short*>(z ? v1g : v0g) + (long)bh * 64 * 1024;
    short* Ob = reinterpret_cast<short*>(z ? o1g : o0g);

    short8 qb[2][2];
#pragma unroll
    for (int qg = 0; qg < 2; ++qg) {
        const short* Qp = Qb + (long)(qt * 128 + qg * 64 + w * 16 + l16) * 64;
        qb[qg][0] = *reinterpret_cast<const short8*>(Qp + quad * 8);
        qb[qg][1] = *reinterpret_cast<const short8*>(Qp + 32 + quad * 8);
    }

    // staging: rows 16w+r8 (bit3=0, f=r8&3) and 16w+8+r8 (bit3=1, f=(r8&3)|4)
    const int r8  = lane >> 3;
    const int sc0 = ((lane & 7) ^ (r8 & 3)) * 8;
    const short* Kg0 = Kb + (long)(16 * w + r8) * 64 + sc0;
    const short* Kg1 = Kb + (long)(16 * w + 8 + r8) * 64 + (sc0 ^ 32);
    const short* Vg0 = Vb + (long)(16 * w + r8) * 1024 + sc0;
    const short* Vg1 = Vb + (long)(16 * w + 8 + r8) * 1024 + (sc0 ^ 32);

    const int jbase = 8 * (l16 >> 2) + (l16 & 3);
    // read-side swizzle constants (row bits expressed via l16)
    const int fKs = (l16 & 3) | (((l16 >> 2) & 1) << 2);
    const int s0  = (quad ^ fKs) * 8;
    const int fVs = (l16 & 3) | (((l16 >> 3) & 1) << 2);
    const int sv  = (quad ^ fVs) * 8;

    f32x4 o[2][4] = {};
    float li[2] = {0.f, 0.f};

    // prologue: tile 0 -> buf 0
    gload16(Kg0, smem + w * 1024); gload16(Kg1, smem + w * 1024 + 512);
    gload16(Vg0, smem + 4096 + w * 1024); gload16(Vg1, smem + 4096 + w * 1024 + 512);

    int bcur = 0;
#pragma unroll 1
    for (int iter = 0; iter < 16; ++iter) {
        int bnext = bcur + 1; if (bnext == 3) bnext = 0;
        if (iter < 15) {   // stage tile t+1 into beta(t+1)
            short* sb = smem + bnext * 8192;
            const long ko = (long)(iter + 1) * 4096;   // K: 64 t-rows * 64 shorts
            const long vo = (long)(iter + 1) * 64;     // V: within-row t offset
            gload16(Kg0 + ko, sb + w * 1024);
            gload16(Kg1 + ko, sb + w * 1024 + 512);
            gload16(Vg0 + vo, sb + 4096 + w * 1024);
            gload16(Vg1 + vo, sb + 4096 + w * 1024 + 512);
            asm volatile("s_waitcnt vmcnt(4)" ::: "memory");
        } else {
            asm volatile("s_waitcnt vmcnt(0)" ::: "memory");
        }
        __builtin_amdgcn_s_barrier();
        __builtin_amdgcn_sched_barrier(0);

        const short* Ks = smem + bcur * 8192;
        const short* Vs = Ks + 4096;

        f32x4 st[2][4];
        __builtin_amdgcn_s_setprio(1);
#pragma unroll
        for (int g = 0; g < 4; ++g) {
            const int goff = (g >> 1) * 32 + (g & 1) * 4;
            const short* kr = Ks + (jbase + goff) * 64;
            short8 k0 = *reinterpret_cast<const short8*>(kr + s0);
            short8 k1 = *reinterpret_cast<const short8*>(kr + (s0 ^ 32));
#pragma unroll
            for (int qg = 0; qg < 2; ++qg) {
                f32x4 zf = {0.f, 0.f, 0.f, 0.f};
                zf = MFMA_BF16(k0, qb[qg][0], zf);
                zf = MFMA_BF16(k1, qb[qg][1], zf);
                st[qg][g] = zf;
            }
        }
        __builtin_amdgcn_s_setprio(0);

        union { unsigned int u[4]; short8 s; } f0[2], f1[2];
#pragma unroll
        for (int qg = 0; qg < 2; ++qg) {
            float p[4][4];
            float rs = 0.f;
#pragma unroll
            for (int g = 0; g < 4; ++g)
#pragma unroll
                for (int r = 0; r < 4; ++r) {
                    float e = EXP2F(st[qg][g][r]);
                    p[g][r] = e;
                    rs += e;
                }
            li[qg] += rs;
            f0[qg].u[0] = pk2(p[0][0], p[0][1]); f0[qg].u[1] = pk2(p[0][2], p[0][3]);
            f0[qg].u[2] = pk2(p[1][0], p[1][1]); f0[qg].u[3] = pk2(p[1][2], p[1][3]);
            f1[qg].u[0] = pk2(p[2][0], p[2][1]); f1[qg].u[1] = pk2(p[2][2], p[2][3]);
            f1[qg].u[2] = pk2(p[3][0], p[3][1]); f1[qg].u[3] = pk2(p[3][2], p[3][3]);
        }

        __builtin_amdgcn_s_setprio(1);
#pragma unroll
        for (int dt = 0; dt < 4; ++dt) {
            const short* vr = Vs + (dt * 16 + l16) * 64;
            short8 v0 = *reinterpret_cast<const short8*>(vr + sv);
            short8 v1 = *reinterpret_cast<const short8*>(vr + (sv ^ 32));
#pragma unroll
            for (int qg = 0; qg < 2; ++qg) {
                o[qg][dt] = MFMA_BF16(v0, f0[qg].s, o[qg][dt]);
                o[qg][dt] = MFMA_BF16(v1, f1[qg].s, o[qg][dt]);
            }
        }
        __builtin_amdgcn_s_setprio(0);
        bcur = bnext;
    }

    __syncthreads();   // O-staging below reuses smem regions that overlap K/V bufs

#pragma unroll
    for (int qg = 0; qg < 2; ++qg) {
        li[qg] += __shfl_xor(li[qg], 16);
        li[qg] += __shfl_xor(li[qg], 32);
    }

#pragma unroll
    for (int qg = 0; qg < 2; ++qg) {
        short* Os = smem + qg * 5120 + w * 1280;
        const float rl = 1.0f / li[qg];
#pragma unroll
        for (int dt = 0; dt < 4; ++dt) {
            uint2 uu;
            uu.x = pk2(o[qg][dt][0] * rl, o[qg][dt][1] * rl);
            uu.y = pk2(o[qg][dt][2] * rl, o[qg][dt][3] * rl);
            *reinterpret_cast<uint2*>(&Os[l16 * 80 + dt * 16 + quad * 4]) = uu;
        }
#pragma unroll
        for (int p = 0; p < 2; ++p) {
            int row = p * 8 + (lane >> 3);
            int ch = (lane & 7) * 8;
            short8 v = *reinterpret_cast<const short8*>(&Os[row * 80 + ch]);
            *reinterpret_cast<short8*>(&Ob[((long)(b * 1024) + qt * 128 + qg * 64 + w * 16 + row) * 1024 + h * 64 + ch]) = v;
        }
    }
}

extern "C" void kernel_launch(void* const* d_in, const int* in_sizes, int n_in,
                              void* d_out, int out_size, void* d_ws, size_t ws_size,
                              hipStream_t stream) {
    const float* x     = (const float*)d_in[0];
    const float* y     = (const float*)d_in[1];
    const float* Wqkv1 = (const float*)d_in[2];
    const float* Wqkv2 = (const float*)d_in[3];
    const float* Wout1 = (const float*)d_in[4];
    const float* Wout2 = (const float*)d_in[5];

    char* ws = (char*)d_ws;
    bf16* Wqkv1b = (bf16*)(ws + 0);          // 6291456
    bf16* Wqkv2b = (bf16*)(ws + 6291456);    // 6291456
    bf16* Wout1b = (bf16*)(ws + 12582912);   // 2097152
    bf16* Wout2b = (bf16*)(ws + 14680064);   // 2097152
    bf16* xb     = (bf16*)(ws + 16777216);   // 8388608
    bf16* yb     = (bf16*)(ws + 25165824);   // 8388608
    bf16* q1     = (bf16*)(ws + 33554432);   // 8388608  packed [bh][t][d]
    bf16* k1     = (bf16*)(ws + 41943040);   // 8388608
    bf16* v1T    = (bf16*)(ws + 50331648);   // 8388608  [bh][d][t]
    bf16* q2     = (bf16*)(ws + 58720256);   // 8388608
    bf16* k2     = (bf16*)(ws + 67108864);   // 8388608
    bf16* v2T    = (bf16*)(ws + 75497472);   // 8388608 -> 83886080 (80 MB)
    bf16* xo     = xb;                       // xb dead after qkv GEMM
    bf16* yo     = yb;

    static bool s_attr = false;
    if (!s_attr) {
        (void)hipFuncSetAttribute(reinterpret_cast<const void*>(&gemm_qkv128),
                                  hipFuncAttributeMaxDynamicSharedMemorySize, 147456);
        s_attr = true;
    }

    // 1. all converts (x, y, Wout, Wqkv-permuted+scaled)
    cvt_fused<<<dim3(4096, 6), 256, 0, stream>>>(x, y, Wout1, Wout2, Wqkv1, Wqkv2,
                                                 xb, yb, Wout1b, Wout2b, Wqkv1b, Wqkv2b);

    // 2. qkv GEMM: 128x256 triple-buffer single-gate pipeline, 768 blocks = 3 exact CU-rounds
    gemm_qkv128<<<dim3(12, 32, 2), 512, 147456, stream>>>(xb, Wqkv1b, q1, k1, v1T,
                                                          yb, Wqkv2b, q2, k2, v2T);

    // 3. cross attention: z=0: softmax(q2 k1^T) v1 -> xo ; z=1: softmax(q1 k2^T) v2 -> yo
    attn_kernel<<<dim3(64, 8, 2), 256, 0, stream>>>(q2, k1, v1T, xo,
                                                    q1, k2, v2T, yo);

    // 4. output projections (triple-buffer counted-vmcnt pipeline, fp32 epilogue)
    gemm_out<<<dim3(8, 32, 2), 256, 0, stream>>>(xo, Wout1b, (float*)d_out,
                                                 yo, Wout2b, ((float*)d_out) + 4194304);
}

// Round 12
// 235.908 us; speedup vs baseline: 2.9585x; 1.0229x over previous
//
#include <hip/hip_runtime.h>
#include <hip/hip_bf16.h>

typedef __hip_bfloat16 bf16;
typedef __attribute__((ext_vector_type(8))) short short8;
typedef __attribute__((ext_vector_type(4))) short short4v;
typedef __attribute__((ext_vector_type(4))) float f32x4;

#define MFMA_BF16(a, b, c) __builtin_amdgcn_mfma_f32_16x16x32_bf16((a), (b), (c), 0, 0, 0)

// 1/sqrt(E/H) * log2(e) folded into Wqkv q-rows: softmax exps become plain exp2
#define QSCALE 0.1803368860111270f

__device__ __forceinline__ short f2bf(float f) {
    union { bf16 h; short s; } u;
    u.h = __float2bfloat16(f);
    return u.s;
}

#if defined(__has_builtin) && __has_builtin(__builtin_amdgcn_cvt_pk_bf16_f32)
typedef __attribute__((ext_vector_type(2))) __bf16 bf16x2_t;
__device__ __forceinline__ unsigned int pk2(float a, float b) {
    union { bf16x2_t v; unsigned int u; } x;
    x.v = __builtin_amdgcn_cvt_pk_bf16_f32(a, b);
    return x.u;
}
#else
__device__ __forceinline__ unsigned int pk2(float a, float b) {
    union { bf16 h[2]; unsigned int u; } x;
    x.h[0] = __float2bfloat16(a);
    x.h[1] = __float2bfloat16(b);
    return x.u;
}
#endif

// raw v_exp_f32 (skip LLVM's denormal-range fixup: scores are far from -126)
#if defined(__has_builtin) && __has_builtin(__builtin_amdgcn_exp2f)
#define EXP2F(x) __builtin_amdgcn_exp2f(x)
#else
#define EXP2F(x) exp2f(x)
#endif

// async global->LDS, 16B per lane; dest = wave-uniform base + lane*16 (linear)
__device__ __forceinline__ void gload16(const void* g, void* l) {
    __builtin_amdgcn_global_load_lds(
        (const __attribute__((address_space(1))) unsigned int*)g,
        (__attribute__((address_space(3))) unsigned int*)l, 16, 0, 0);
}

// ---------------- ALL converts in one dispatch (grid.y selects tensor / mode) ----------------
__global__ void cvt_fused(const float* __restrict__ x, const float* __restrict__ y,
                          const float* __restrict__ wo1, const float* __restrict__ wo2,
                          const float* __restrict__ wq1, const float* __restrict__ wq2,
                          bf16* __restrict__ ox, bf16* __restrict__ oy,
                          bf16* __restrict__ oo1, bf16* __restrict__ oo2,
                          bf16* __restrict__ oq1, bf16* __restrict__ oq2) {
    const int yb = blockIdx.y;
    if (yb < 4) {
        int i = blockIdx.x * 256 + threadIdx.x;
        const float* src; bf16* dst; int n4;
        switch (yb) {
            case 0:  src = x;   dst = ox;  n4 = 1048576; break;
            case 1:  src = y;   dst = oy;  n4 = 1048576; break;
            case 2:  src = wo1; dst = oo1; n4 = 262144;  break;
            default: src = wo2; dst = oo2; n4 = 262144;  break;
        }
        if (i >= n4) return;
        float4 f = reinterpret_cast<const float4*>(src)[i];
        short4v s;
        s.x = f2bf(f.x); s.y = f2bf(f.y); s.z = f2bf(f.z); s.w = f2bf(f.w);
        reinterpret_cast<short4v*>(dst)[i] = s;
    } else {
        // dest row n' = comp*1024 + h*64 + d  <-  src row d*48 + comp*16 + h
        const int np = blockIdx.x;
        if (np >= 3072) return;
        const int comp = np >> 10, rem = np & 1023, h = rem >> 6, d = rem & 63;
        const int srow = d * 48 + comp * 16 + h;
        const float* src = ((yb == 5) ? wq2 : wq1) + (long)srow * 1024;
        bf16* dst = ((yb == 5) ? oq2 : oq1) + (long)np * 1024;
        const float sc = (comp == 0) ? QSCALE : 1.0f;
        int t = threadIdx.x;
        float4 f = reinterpret_cast<const float4*>(src)[t];
        short4v s;
        s.x = f2bf(f.x * sc); s.y = f2bf(f.y * sc); s.z = f2bf(f.z * sc); s.w = f2bf(f.w * sc);
        reinterpret_cast<short4v*>(dst)[t] = s;
    }
}

// ---------------- 128x256 qkv GEMM, BK=64, 8 waves, TRIPLE-buffer single-gate pipeline ----------------
// (SESSION-BEST, unchanged from rounds 6/11: qkv ~60.3 us)
__global__ __launch_bounds__(512, 2)
void gemm_qkv128(const bf16* __restrict__ A0g, const bf16* __restrict__ B0g,
                 void* o0a, void* o0b, void* o0c,
                 const bf16* __restrict__ A1g, const bf16* __restrict__ B1g,
                 void* o1a, void* o1b, void* o1c) {
    extern __shared__ short smem[];   // 73728 shorts = 144KB (3 bufs x 24576)
    const int z = blockIdx.z;
    const short* A = reinterpret_cast<const short*>(z ? A1g : A0g);
    const short* B = reinterpret_cast<const short*>(z ? B1g : B0g);
    const int tid  = threadIdx.x;
    const int lane = tid & 63;
    const int w    = tid >> 6;        // 0..7
    const int quad = lane >> 4;
    const int l16  = lane & 15;
    const long M0 = (long)blockIdx.y * 128;
    const long N0 = (long)blockIdx.x * 256;

    const int wm = w >> 2;            // wave M-group (0..1), 64 rows each
    const int wn = w & 3;             // wave N-group (0..3), 32 cols per B-half
    const int cA0  = (quad ^ (l16 & 7)) * 8;            // kk=0 chunk (shorts); kk=1 -> ^32
    const int aoff = wm * 4096 + l16 * 64;              // A row base (shorts, within buf)
    const int boff = 8192 + wn * 2048 + l16 * 64;       // B row base within buf
    const int w512 = w * 512;

    const short* Asrc = A + (M0 + w * 8 + (lane >> 3)) * 1024 + ((lane & 7) ^ (lane >> 3)) * 8;
    const short* Bsrc = B + (N0 + w * 8 + (lane >> 3)) * 1024 + ((lane & 7) ^ (lane >> 3)) * 8;

    f32x4 acc[2][4][2] = {};
    short8 af[4][2], bfv[2][2];

#define SA128(tt, nbase) do { \
    const short* _s = Asrc + (tt) * 64; \
    short* _d = smem + (nbase) + w512; \
    gload16(_s, _d); gload16(_s + 65536, _d + 4096); } while (0)
#define SB128(half, tt, nbase) do { \
    const short* _s = Bsrc + (half) * 131072 + (tt) * 64; \
    short* _d = smem + (nbase) + 8192 + (half) * 8192 + w512; \
    gload16(_s, _d); gload16(_s + 65536, _d + 4096); } while (0)
#define RDA128(bbv) do { \
    _Pragma("unroll") for (int mt = 0; mt < 4; ++mt) { \
        const short* _p = &smem[(bbv) + aoff + mt * 1024]; \
        af[mt][0] = *reinterpret_cast<const short8*>(_p + cA0); \
        af[mt][1] = *reinterpret_cast<const short8*>(_p + (cA0 ^ 32)); } } while (0)
#define RDB128(Bh, bbv) do { \
    _Pragma("unroll") for (int nt = 0; nt < 2; ++nt) { \
        const short* _p = &smem[(bbv) + (Bh) * 8192 + boff + nt * 1024]; \
        bfv[nt][0] = *reinterpret_cast<const short8*>(_p + cA0); \
        bfv[nt][1] = *reinterpret_cast<const short8*>(_p + (cA0 ^ 32)); } } while (0)
#define MM128(p) do { \
    __builtin_amdgcn_s_setprio(1); \
    _Pragma("unroll") for (int mt = 0; mt < 4; ++mt) \
    _Pragma("unroll") for (int nt = 0; nt < 2; ++nt) { \
        acc[p][mt][nt] = MFMA_BF16(af[mt][0], bfv[nt][0], acc[p][mt][nt]); \
        acc[p][mt][nt] = MFMA_BF16(af[mt][1], bfv[nt][1], acc[p][mt][nt]); } \
    __builtin_amdgcn_s_setprio(0); } while (0)

    // prologue: K-tile 0 fully staged into buf0 (6 loads/wave: A, B0, B1)
    SA128(0, 0); SB128(0, 0, 0); SB128(1, 0, 0);

    int bcur = 0;
#pragma unroll 1
    for (int t = 0; t < 16; ++t) {
        int bnext = bcur + 1; if (bnext == 3) bnext = 0;
        if (t < 15) {
            const int nb = bnext * 24576;
            SA128(t + 1, nb); SB128(0, t + 1, nb); SB128(1, t + 1, nb);
            asm volatile("s_waitcnt vmcnt(6)" ::: "memory");
        } else {
            asm volatile("s_waitcnt vmcnt(0)" ::: "memory");
        }
        __builtin_amdgcn_s_barrier();
        __builtin_amdgcn_sched_barrier(0);

        const int bb = bcur * 24576;
        RDA128(bb);
        RDB128(0, bb);
        MM128(0);
        RDB128(1, bb);
        MM128(1);
        bcur = bnext;
    }

    __syncthreads();   // epilogue ws scratch overlaps the tail compute buffer

    if (blockIdx.x < 8) {
        // q (x<4) / k (x 4..7), packed [bh][t][d]
        short* dst = reinterpret_cast<short*>(blockIdx.x < 4 ? (z ? o1a : o0a)
                                                             : (z ? o1b : o0b));
        const int b = (int)(M0 >> 10);
        const int t00 = ((int)M0 & 1023) + wm * 64 + quad * 4;
        const int hd00 = ((int)blockIdx.x & 3) * 256 + wn * 32;
#pragma unroll
        for (int Bh = 0; Bh < 2; ++Bh)
#pragma unroll
            for (int nt = 0; nt < 2; ++nt) {
                const int hd = hd00 + Bh * 128 + nt * 16 + l16;
                const int h = hd >> 6, d = hd & 63;
                short* dp = dst + (long)(b * 16 + h) * 65536 + d;
#pragma unroll
                for (int mt = 0; mt < 4; ++mt)
#pragma unroll
                    for (int r = 0; r < 4; ++r)
                        dp[(long)(t00 + mt * 16 + r) * 64] = f2bf(acc[Bh][mt][nt][r]);
            }
    } else {
        // V: per-wave LDS transpose -> vT [bh][d][t], coalesced 16B stores
        short* vT = reinterpret_cast<short*>(z ? o1c : o0c);
        const int b = (int)(M0 >> 10);
        const int hd00 = ((int)blockIdx.x - 8) * 256 + wn * 32;
        short* ws = smem + w * 2304;     // 32 cols x 72 shorts, wave-private
        const int c8 = (lane & 7) * 8;
        const int colr = lane >> 3;
        const int tb = ((int)M0 & 1023) + wm * 64 + c8;
#pragma unroll
        for (int Bh = 0; Bh < 2; ++Bh) {
#pragma unroll
            for (int nt = 0; nt < 2; ++nt)
#pragma unroll
                for (int mt = 0; mt < 4; ++mt) {
                    uint2 uu;
                    uu.x = pk2(acc[Bh][mt][nt][0], acc[Bh][mt][nt][1]);
                    uu.y = pk2(acc[Bh][mt][nt][2], acc[Bh][mt][nt][3]);
                    *reinterpret_cast<uint2*>(&ws[(nt * 16 + l16) * 72 + mt * 16 + quad * 4]) = uu;
                }
#pragma unroll
            for (int q4 = 0; q4 < 4; ++q4) {
                const int col = q4 * 8 + colr;
                const int hd = hd00 + Bh * 128 + col;
                const int h = hd >> 6, d = hd & 63;
                short8 v = *reinterpret_cast<const short8*>(&ws[col * 72 + c8]);
                *reinterpret_cast<short8*>(&vT[(long)(b * 16 + h) * 65536 + (long)d * 1024 + tb]) = v;
            }
        }
    }
#undef SA128
#undef SB128
#undef RDA128
#undef RDB128
#undef MM128
}

// ---------------- out-proj GEMM: 128x128, TRIPLE-buffer counted-vmcnt pipeline ----------------
// (unchanged — passed in rounds 4-11)
__global__ __launch_bounds__(256)
void gemm_out(const bf16* __restrict__ A0g, const bf16* __restrict__ B0g, float* __restrict__ C0,
              const bf16* __restrict__ A1g, const bf16* __restrict__ B1g, float* __restrict__ C1) {
    __shared__ short smem2[24576];   // 3 bufs x (A 4096 + B 4096)
    const int z = blockIdx.z;
    const short* A = reinterpret_cast<const short*>(z ? A1g : A0g);
    const short* B = reinterpret_cast<const short*>(z ? B1g : B0g);
    const int tid  = threadIdx.x;
    const int lane = tid & 63;
    const int w    = tid >> 6;
    const int wr   = w >> 1;
    const int wc   = w & 1;
    const int quad = lane >> 4;
    const int l16  = lane & 15;
    const long bM = (long)blockIdx.y * 128;

    f32x4 acc[4][4] = {};

    const int sr  = lane >> 2;
    const int scs = ((lane & 3) ^ (sr & 3)) * 8;
    const short* Ag0 = A + (bM + 32 * w + sr) * 1024 + scs;
    const short* Ag1 = Ag0 + 16 * 1024;
    const short* Bg0 = B + ((long)blockIdx.x * 128 + 32 * w + sr) * 1024 + scs;
    const short* Bg1 = Bg0 + 16 * 1024;
    const int sq = (quad ^ (l16 & 3)) * 8;

    {   // prologue: tile 0 -> buf 0
        short* sb = smem2;
        gload16(Ag0, sb + w * 1024);
        gload16(Ag1, sb + w * 1024 + 512);
        gload16(Bg0, sb + 4096 + w * 1024);
        gload16(Bg1, sb + 4096 + w * 1024 + 512);
    }

    int bcur = 0;
#pragma unroll 1
    for (int iter = 0; iter < 32; ++iter) {
        int bnext = bcur + 1; if (bnext == 3) bnext = 0;
        if (iter < 31) {
            const int koff = (iter + 1) * 32;
            short* sb = smem2 + bnext * 8192;
            gload16(Ag0 + koff, sb + w * 1024);
            gload16(Ag1 + koff, sb + w * 1024 + 512);
            gload16(Bg0 + koff, sb + 4096 + w * 1024);
            gload16(Bg1 + koff, sb + 4096 + w * 1024 + 512);
            asm volatile("s_waitcnt vmcnt(4)" ::: "memory");
        } else {
            asm volatile("s_waitcnt vmcnt(0)" ::: "memory");
        }
        __builtin_amdgcn_s_barrier();
        __builtin_amdgcn_sched_barrier(0);

        const short* Ab = smem2 + bcur * 8192;
        const short* Bb = Ab + 4096;

        short8 af[4], bfr[4];
#pragma unroll
        for (int mt = 0; mt < 4; ++mt)
            af[mt] = *reinterpret_cast<const short8*>(&Ab[(wr * 64 + mt * 16 + l16) * 32 + sq]);
#pragma unroll
        for (int nt = 0; nt < 4; ++nt)
            bfr[nt] = *reinterpret_cast<const short8*>(&Bb[(wc * 64 + nt * 16 + l16) * 32 + sq]);
        __builtin_amdgcn_s_setprio(1);
#pragma unroll
        for (int mt = 0; mt < 4; ++mt)
#pragma unroll
            for (int nt = 0; nt < 4; ++nt)
                acc[mt][nt] = MFMA_BF16(af[mt], bfr[nt], acc[mt][nt]);
        __builtin_amdgcn_s_setprio(0);
        bcur = bnext;
    }

    float* C = z ? C1 : C0;
    const long crow = bM + wr * 64 + quad * 4;
    const long ccol = (long)blockIdx.x * 128 + wc * 64 + l16;
#pragma unroll
    for (int mt = 0; mt < 4; ++mt)
#pragma unroll
        for (int nt = 0; nt < 4; ++nt)
#pragma unroll
            for (int r = 0; r < 4; ++r)
                C[(crow + mt * 16 + r) * 1024L + ccol + nt * 16] = acc[mt][nt][r];
}

// ---------------- flash attention: 2 Q-tiles per block (K/V frag reuse), 3-buf counted gate ----------------
// R12 change: each block processes Q-tiles {2*by, 2*by+1} against the shared K/V stream.
// K-frags held in registers (kf[4][2]) and reused for both Q-tiles' QK^T; V-frags reused for
// both PV -> MFMA per LDS byte doubles (64 MFMA / 16 b128 reads per iter/wave); K/V staging
// + HBM traffic halves; grid halves to 64x4x2 = 512 = 2 blocks/CU, both co-resident
// (48KB LDS allows 3). Gate/swizzle/staging/epilogue identical to the rounds-4..11 kernel.
__global__ __launch_bounds__(256, 2)
void attn_kernel(const bf16* __restrict__ q0g, const bf16* __restrict__ k0g,
                 const bf16* __restrict__ v0g, bf16* __restrict__ o0g,
                 const bf16* __restrict__ q1g, const bf16* __restrict__ k1g,
                 const bf16* __restrict__ v1g, bf16* __restrict__ o1g) {
    __shared__ short smem[24576];   // 3 bufs x (K 4096 + V 4096) shorts = 48KB
    const int bh = blockIdx.x;
    const int qt0 = blockIdx.y << 1;   // Q-tile pair
    const int z = blockIdx.z;
    const int b = bh >> 4, h = bh & 15;
    const int tid = threadIdx.x, lane = tid & 63, w = tid >> 6;
    const int quad = lane >> 4, l16 = lane & 15;

    const short* Qb = reinterpret_cast<const short*>(z ? q1g : q0g) + (long)bh * 1024 * 64;
    const short* Kb = reinterpret_cast<const short*>(z ? k1g : k0g) + (long)bh * 1024 * 64;
    const short* Vb = reinterpret_cast<const short*>(z ? v1g : v0g) + (long)bh * 64 * 1024;
    short* Ob = reinterpret_cast<short*>(z ? o1g : o0g);

    short8 qb[2][2][2];
#pragma unroll
    for (int q2 = 0; q2 < 2; ++q2)
#pragma unroll
        for (int qg = 0; qg < 2; ++qg) {
            const short* Qp = Qb + (long)((qt0 + q2) * 128 + qg * 64 + w * 16 + l16) * 64;
            qb[q2][qg][0] = *reinterpret_cast<const short8*>(Qp + quad * 8);
            qb[q2][qg][1] = *reinterpret_cast<const short8*>(Qp + 32 + quad * 8);
        }

    // staging: rows 16w+r8 (bit3=0, f=r8&3) and 16w+8+r8 (bit3=1, f=(r8&3)|4)
    const int r8  = lane >> 3;
    const int sc0 = ((lane & 7) ^ (r8 & 3)) * 8;
    const short* Kg0 = Kb + (long)(16 * w + r8) * 64 + sc0;
    const short* Kg1 = Kb + (long)(16 * w + 8 + r8) * 64 + (sc0 ^ 32);
    const short* Vg0 = Vb + (long)(16 * w + r8) * 1024 + sc0;
    const short* Vg1 = Vb + (long)(16 * w + 8 + r8) * 1024 + (sc0 ^ 32);

    const int jbase = 8 * (l16 >> 2) + (l16 & 3);
    // read-side swizzle constants (row bits expressed via l16)
    const int fKs = (l16 & 3) | (((l16 >> 2) & 1) << 2);
    const int s0  = (quad ^ fKs) * 8;
    const int fVs = (l16 & 3) | (((l16 >> 3) & 1) << 2);
    const int sv  = (quad ^ fVs) * 8;

    f32x4 o[2][2][4] = {};
    float li[2][2] = {{0.f, 0.f}, {0.f, 0.f}};

    // prologue: tile 0 -> buf 0
    gload16(Kg0, smem + w * 1024); gload16(Kg1, smem + w * 1024 + 512);
    gload16(Vg0, smem + 4096 + w * 1024); gload16(Vg1, smem + 4096 + w * 1024 + 512);

    int bcur = 0;
#pragma unroll 1
    for (int iter = 0; iter < 16; ++iter) {
        int bnext = bcur + 1; if (bnext == 3) bnext = 0;
        if (iter < 15) {   // stage tile t+1 into beta(t+1)
            short* sb = smem + bnext * 8192;
            const long ko = (long)(iter + 1) * 4096;   // K: 64 t-rows * 64 shorts
            const long vo = (long)(iter + 1) * 64;     // V: within-row t offset
            gload16(Kg0 + ko, sb + w * 1024);
            gload16(Kg1 + ko, sb + w * 1024 + 512);
            gload16(Vg0 + vo, sb + 4096 + w * 1024);
            gload16(Vg1 + vo, sb + 4096 + w * 1024 + 512);
            asm volatile("s_waitcnt vmcnt(4)" ::: "memory");
        } else {
            asm volatile("s_waitcnt vmcnt(0)" ::: "memory");
        }
        __builtin_amdgcn_s_barrier();
        __builtin_amdgcn_sched_barrier(0);

        const short* Ks = smem + bcur * 8192;
        const short* Vs = Ks + 4096;

        // K-frags once, reused for both Q-tiles
        short8 kf[4][2];
#pragma unroll
        for (int g = 0; g < 4; ++g) {
            const int goff = (g >> 1) * 32 + (g & 1) * 4;
            const short* kr = Ks + (jbase + goff) * 64;
            kf[g][0] = *reinterpret_cast<const short8*>(kr + s0);
            kf[g][1] = *reinterpret_cast<const short8*>(kr + (s0 ^ 32));
        }

        union { unsigned int u[4]; short8 s; } f0[2][2], f1[2][2];
#pragma unroll
        for (int q2 = 0; q2 < 2; ++q2) {
            f32x4 st[2][4];
            __builtin_amdgcn_s_setprio(1);
#pragma unroll
            for (int g = 0; g < 4; ++g)
#pragma unroll
                for (int qg = 0; qg < 2; ++qg) {
                    f32x4 zf = {0.f, 0.f, 0.f, 0.f};
                    zf = MFMA_BF16(kf[g][0], qb[q2][qg][0], zf);
                    zf = MFMA_BF16(kf[g][1], qb[q2][qg][1], zf);
                    st[qg][g] = zf;
                }
            __builtin_amdgcn_s_setprio(0);

#pragma unroll
            for (int qg = 0; qg < 2; ++qg) {
                float p[4][4];
                float rs = 0.f;
#pragma unroll
                for (int g = 0; g < 4; ++g)
#pragma unroll
                    for (int r = 0; r < 4; ++r) {
                        float e = EXP2F(st[qg][g][r]);
                        p[g][r] = e;
                        rs += e;
                    }
                li[q2][qg] += rs;
                f0[q2][qg].u[0] = pk2(p[0][0], p[0][1]); f0[q2][qg].u[1] = pk2(p[0][2], p[0][3]);
                f0[q2][qg].u[2] = pk2(p[1][0], p[1][1]); f0[q2][qg].u[3] = pk2(p[1][2], p[1][3]);
                f1[q2][qg].u[0] = pk2(p[2][0], p[2][1]); f1[q2][qg].u[1] = pk2(p[2][2], p[2][3]);
                f1[q2][qg].u[2] = pk2(p[3][0], p[3][1]); f1[q2][qg].u[3] = pk2(p[3][2], p[3][3]);
            }
        }

        // V-frags once, reused for both Q-tiles
        __builtin_amdgcn_s_setprio(1);
#pragma unroll
        for (int dt = 0; dt < 4; ++dt) {
            const short* vr = Vs + (dt * 16 + l16) * 64;
            short8 v0 = *reinterpret_cast<const short8*>(vr + sv);
            short8 v1 = *reinterpret_cast<const short8*>(vr + (sv ^ 32));
#pragma unroll
            for (int q2 = 0; q2 < 2; ++q2)
#pragma unroll
                for (int qg = 0; qg < 2; ++qg) {
                    o[q2][qg][dt] = MFMA_BF16(v0, f0[q2][qg].s, o[q2][qg][dt]);
                    o[q2][qg][dt] = MFMA_BF16(v1, f1[q2][qg].s, o[q2][qg][dt]);
                }
        }
        __builtin_amdgcn_s_setprio(0);
        bcur = bnext;
    }

    __syncthreads();   // O-staging below reuses smem regions that overlap K/V bufs

#pragma unroll
    for (int q2 = 0; q2 < 2; ++q2)
#pragma unroll
        for (int qg = 0; qg < 2; ++qg) {
            li[q2][qg] += __shfl_xor(li[q2][qg], 16);
            li[q2][qg] += __shfl_xor(li[q2][qg], 32);
        }

#pragma unroll
    for (int q2 = 0; q2 < 2; ++q2)
#pragma unroll
        for (int qg = 0; qg < 2; ++qg) {
            short* Os = smem + qg * 5120 + w * 1280;   // wave-private; same-wave DS ordering
            const float rl = 1.0f / li[q2][qg];
#pragma unroll
            for (int dt = 0; dt < 4; ++dt) {
                uint2 uu;
                uu.x = pk2(o[q2][qg][dt][0] * rl, o[q2][qg][dt][1] * rl);
                uu.y = pk2(o[q2][qg][dt][2] * rl, o[q2][qg][dt][3] * rl);
                *reinterpret_cast<uint2*>(&Os[l16 * 80 + dt * 16 + quad * 4]) = uu;
            }
#pragma unroll
            for (int p = 0; p < 2; ++p) {
                int row = p * 8 + (lane >> 3);
                int ch = (lane & 7) * 8;
                short8 v = *reinterpret_cast<const short8*>(&Os[row * 80 + ch]);
                *reinterpret_cast<short8*>(&Ob[((long)(b * 1024) + (qt0 + q2) * 128 + qg * 64 + w * 16 + row) * 1024 + h * 64 + ch]) = v;
            }
        }
}

extern "C" void kernel_launch(void* const* d_in, const int* in_sizes, int n_in,
                              void* d_out, int out_size, void* d_ws, size_t ws_size,
                              hipStream_t stream) {
    const float* x     = (const float*)d_in[0];
    const float* y     = (const float*)d_in[1];
    const float* Wqkv1 = (const float*)d_in[2];
    const float* Wqkv2 = (const float*)d_in[3];
    const float* Wout1 = (const float*)d_in[4];
    const float* Wout2 = (const float*)d_in[5];

    char* ws = (char*)d_ws;
    bf16* Wqkv1b = (bf16*)(ws + 0);          // 6291456
    bf16* Wqkv2b = (bf16*)(ws + 6291456);    // 6291456
    bf16* Wout1b = (bf16*)(ws + 12582912);   // 2097152
    bf16* Wout2b = (bf16*)(ws + 14680064);   // 2097152
    bf16* xb     = (bf16*)(ws + 16777216);   // 8388608
    bf16* yb     = (bf16*)(ws + 25165824);   // 8388608
    bf16* q1     = (bf16*)(ws + 33554432);   // 8388608  packed [bh][t][d]
    bf16* k1     = (bf16*)(ws + 41943040);   // 8388608
    bf16* v1T    = (bf16*)(ws + 50331648);   // 8388608  [bh][d][t]
    bf16* q2     = (bf16*)(ws + 58720256);   // 8388608
    bf16* k2     = (bf16*)(ws + 67108864);   // 8388608
    bf16* v2T    = (bf16*)(ws + 75497472);   // 8388608 -> 83886080 (80 MB)
    bf16* xo     = xb;                       // xb dead after qkv GEMM
    bf16* yo     = yb;

    static bool s_attr = false;
    if (!s_attr) {
        (void)hipFuncSetAttribute(reinterpret_cast<const void*>(&gemm_qkv128),
                                  hipFuncAttributeMaxDynamicSharedMemorySize, 147456);
        s_attr = true;
    }

    // 1. all converts (x, y, Wout, Wqkv-permuted+scaled)
    cvt_fused<<<dim3(4096, 6), 256, 0, stream>>>(x, y, Wout1, Wout2, Wqkv1, Wqkv2,
                                                 xb, yb, Wout1b, Wout2b, Wqkv1b, Wqkv2b);

    // 2. qkv GEMM: 128x256 triple-buffer single-gate pipeline, 768 blocks = 3 exact CU-rounds
    gemm_qkv128<<<dim3(12, 32, 2), 512, 147456, stream>>>(xb, Wqkv1b, q1, k1, v1T,
                                                          yb, Wqkv2b, q2, k2, v2T);

    // 3. cross attention (2 Q-tiles/block): z=0: softmax(q2 k1^T) v1 -> xo ; z=1: ... -> yo
    attn_kernel<<<dim3(64, 4, 2), 256, 0, stream>>>(q2, k1, v1T, xo,
                                                    q1, k2, v2T, yo);

    // 4. output projections (triple-buffer counted-vmcnt pipeline, fp32 epilogue)
    gemm_out<<<dim3(8, 32, 2), 256, 0, stream>>>(xo, Wout1b, (float*)d_out,
                                                 yo, Wout2b, ((float*)d_out) + 4194304);
}

// Round 13
// 231.358 us; speedup vs baseline: 3.0166x; 1.0197x over previous
//
#include <hip/hip_runtime.h>
#include <hip/hip_bf16.h>

typedef __hip_bfloat16 bf16;
typedef __attribute__((ext_vector_type(8))) short short8;
typedef __attribute__((ext_vector_type(4))) short short4v;
typedef __attribute__((ext_vector_type(4))) float f32x4;

#define MFMA_BF16(a, b, c) __builtin_amdgcn_mfma_f32_16x16x32_bf16((a), (b), (c), 0, 0, 0)

// 1/sqrt(E/H) * log2(e) folded into Wqkv q-rows: softmax exps become plain exp2
#define QSCALE 0.1803368860111270f

__device__ __forceinline__ short f2bf(float f) {
    union { bf16 h; short s; } u;
    u.h = __float2bfloat16(f);
    return u.s;
}

#if defined(__has_builtin) && __has_builtin(__builtin_amdgcn_cvt_pk_bf16_f32)
typedef __attribute__((ext_vector_type(2))) __bf16 bf16x2_t;
__device__ __forceinline__ unsigned int pk2(float a, float b) {
    union { bf16x2_t v; unsigned int u; } x;
    x.v = __builtin_amdgcn_cvt_pk_bf16_f32(a, b);
    return x.u;
}
#else
__device__ __forceinline__ unsigned int pk2(float a, float b) {
    union { bf16 h[2]; unsigned int u; } x;
    x.h[0] = __float2bfloat16(a);
    x.h[1] = __float2bfloat16(b);
    return x.u;
}
#endif

// raw v_exp_f32 (skip LLVM's denormal-range fixup: scores are far from -126)
#if defined(__has_builtin) && __has_builtin(__builtin_amdgcn_exp2f)
#define EXP2F(x) __builtin_amdgcn_exp2f(x)
#else
#define EXP2F(x) exp2f(x)
#endif

// async global->LDS, 16B per lane; dest = wave-uniform base + lane*16 (linear)
__device__ __forceinline__ void gload16(const void* g, void* l) {
    __builtin_amdgcn_global_load_lds(
        (const __attribute__((address_space(1))) unsigned int*)g,
        (__attribute__((address_space(3))) unsigned int*)l, 16, 0, 0);
}

// ---------------- ALL converts, compact 1D grid (no idle blocks) ----------------
// segments: [0,4096) x | [4096,8192) y | [8192,9216) wo1 | [9216,10240) wo2
//           [10240,13312) wq1 | [13312,16384) wq2
__global__ void cvt_fused(const float* __restrict__ x, const float* __restrict__ y,
                          const float* __restrict__ wo1, const float* __restrict__ wo2,
                          const float* __restrict__ wq1, const float* __restrict__ wq2,
                          bf16* __restrict__ ox, bf16* __restrict__ oy,
                          bf16* __restrict__ oo1, bf16* __restrict__ oo2,
                          bf16* __restrict__ oq1, bf16* __restrict__ oq2) {
    const int gb = blockIdx.x;
    if (gb < 10240) {
        const float* src; bf16* dst; int i;
        if (gb < 4096)       { src = x;   dst = ox;  i = gb * 256 + threadIdx.x; }
        else if (gb < 8192)  { src = y;   dst = oy;  i = (gb - 4096) * 256 + threadIdx.x; }
        else if (gb < 9216)  { src = wo1; dst = oo1; i = (gb - 8192) * 256 + threadIdx.x; }
        else                 { src = wo2; dst = oo2; i = (gb - 9216) * 256 + threadIdx.x; }
        float4 f = reinterpret_cast<const float4*>(src)[i];
        short4v s;
        s.x = f2bf(f.x); s.y = f2bf(f.y); s.z = f2bf(f.z); s.w = f2bf(f.w);
        reinterpret_cast<short4v*>(dst)[i] = s;
    } else {
        // dest row n' = comp*1024 + h*64 + d  <-  src row d*48 + comp*16 + h
        const int isW2 = gb >= 13312;
        const int np = gb - (isW2 ? 13312 : 10240);
        const int comp = np >> 10, rem = np & 1023, h = rem >> 6, d = rem & 63;
        const int srow = d * 48 + comp * 16 + h;
        const float* src = (isW2 ? wq2 : wq1) + (long)srow * 1024;
        bf16* dst = (isW2 ? oq2 : oq1) + (long)np * 1024;
        const float sc = (comp == 0) ? QSCALE : 1.0f;
        int t = threadIdx.x;
        float4 f = reinterpret_cast<const float4*>(src)[t];
        short4v s;
        s.x = f2bf(f.x * sc); s.y = f2bf(f.y * sc); s.z = f2bf(f.z * sc); s.w = f2bf(f.w * sc);
        reinterpret_cast<short4v*>(dst)[t] = s;
    }
}

// ---------------- 128x256 qkv GEMM, BK=64, 8 waves, TRIPLE-buffer + XCD swizzle ----------------
// R13 change: bijective XCD-aware block swizzle (768 blocks = 8 XCDs x 96 exactly).
// nid = (oid%8)*96 + oid/8 gives each XCD a contiguous 96-block chunk = 8 y-values x all
// 12 x-values (z fixed) -> each A panel (256KB) fetched once per XCD, reused 12x from L2
// (8 panels = 2MB < 4MB L2). Attacks the measured 91MB FETCH (ideal ~28MB).
// Inner loop/schedule byte-identical to the session-best rounds 6/11/12 kernel.
__global__ __launch_bounds__(512, 2)
void gemm_qkv128(const bf16* __restrict__ A0g, const bf16* __restrict__ B0g,
                 void* o0a, void* o0b, void* o0c,
                 const bf16* __restrict__ A1g, const bf16* __restrict__ B1g,
                 void* o1a, void* o1b, void* o1c) {
    extern __shared__ short smem[];   // 73728 shorts = 144KB (3 bufs x 24576)
    // bijective XCD swizzle: oid -> nid, decode (bx, by, bz) against grid (12,32,2)
    const int oid = (int)(blockIdx.x + 12 * (blockIdx.y + 32 * blockIdx.z));
    const int nid = (oid & 7) * 96 + (oid >> 3);
    const int bx = nid % 12;
    const int by = (nid / 12) & 31;
    const int bz = nid / 384;

    const int z = bz;
    const short* A = reinterpret_cast<const short*>(z ? A1g : A0g);
    const short* B = reinterpret_cast<const short*>(z ? B1g : B0g);
    const int tid  = threadIdx.x;
    const int lane = tid & 63;
    const int w    = tid >> 6;        // 0..7
    const int quad = lane >> 4;
    const int l16  = lane & 15;
    const long M0 = (long)by * 128;
    const long N0 = (long)bx * 256;

    const int wm = w >> 2;            // wave M-group (0..1), 64 rows each
    const int wn = w & 3;             // wave N-group (0..3), 32 cols per B-half
    const int cA0  = (quad ^ (l16 & 7)) * 8;            // kk=0 chunk (shorts); kk=1 -> ^32
    const int aoff = wm * 4096 + l16 * 64;              // A row base (shorts, within buf)
    const int boff = 8192 + wn * 2048 + l16 * 64;       // B row base within buf
    const int w512 = w * 512;

    const short* Asrc = A + (M0 + w * 8 + (lane >> 3)) * 1024 + ((lane & 7) ^ (lane >> 3)) * 8;
    const short* Bsrc = B + (N0 + w * 8 + (lane >> 3)) * 1024 + ((lane & 7) ^ (lane >> 3)) * 8;

    f32x4 acc[2][4][2] = {};
    short8 af[4][2], bfv[2][2];

#define SA128(tt, nbase) do { \
    const short* _s = Asrc + (tt) * 64; \
    short* _d = smem + (nbase) + w512; \
    gload16(_s, _d); gload16(_s + 65536, _d + 4096); } while (0)
#define SB128(half, tt, nbase) do { \
    const short* _s = Bsrc + (half) * 131072 + (tt) * 64; \
    short* _d = smem + (nbase) + 8192 + (half) * 8192 + w512; \
    gload16(_s, _d); gload16(_s + 65536, _d + 4096); } while (0)
#define RDA128(bbv) do { \
    _Pragma("unroll") for (int mt = 0; mt < 4; ++mt) { \
        const short* _p = &smem[(bbv) + aoff + mt * 1024]; \
        af[mt][0] = *reinterpret_cast<const short8*>(_p + cA0); \
        af[mt][1] = *reinterpret_cast<const short8*>(_p + (cA0 ^ 32)); } } while (0)
#define RDB128(Bh, bbv) do { \
    _Pragma("unroll") for (int nt = 0; nt < 2; ++nt) { \
        const short* _p = &smem[(bbv) + (Bh) * 8192 + boff + nt * 1024]; \
        bfv[nt][0] = *reinterpret_cast<const short8*>(_p + cA0); \
        bfv[nt][1] = *reinterpret_cast<const short8*>(_p + (cA0 ^ 32)); } } while (0)
#define MM128(p) do { \
    __builtin_amdgcn_s_setprio(1); \
    _Pragma("unroll") for (int mt = 0; mt < 4; ++mt) \
    _Pragma("unroll") for (int nt = 0; nt < 2; ++nt) { \
        acc[p][mt][nt] = MFMA_BF16(af[mt][0], bfv[nt][0], acc[p][mt][nt]); \
        acc[p][mt][nt] = MFMA_BF16(af[mt][1], bfv[nt][1], acc[p][mt][nt]); } \
    __builtin_amdgcn_s_setprio(0); } while (0)

    // prologue: K-tile 0 fully staged into buf0 (6 loads/wave: A, B0, B1)
    SA128(0, 0); SB128(0, 0, 0); SB128(1, 0, 0);

    int bcur = 0;
#pragma unroll 1
    for (int t = 0; t < 16; ++t) {
        int bnext = bcur + 1; if (bnext == 3) bnext = 0;
        if (t < 15) {
            const int nb = bnext * 24576;
            SA128(t + 1, nb); SB128(0, t + 1, nb); SB128(1, t + 1, nb);
            asm volatile("s_waitcnt vmcnt(6)" ::: "memory");
        } else {
            asm volatile("s_waitcnt vmcnt(0)" ::: "memory");
        }
        __builtin_amdgcn_s_barrier();
        __builtin_amdgcn_sched_barrier(0);

        const int bb = bcur * 24576;
        RDA128(bb);
        RDB128(0, bb);
        MM128(0);
        RDB128(1, bb);
        MM128(1);
        bcur = bnext;
    }

    __syncthreads();   // epilogue ws scratch overlaps the tail compute buffer

    if (bx < 8) {
        // q (x<4) / k (x 4..7), packed [bh][t][d]
        short* dst = reinterpret_cast<short*>(bx < 4 ? (z ? o1a : o0a)
                                                     : (z ? o1b : o0b));
        const int b = (int)(M0 >> 10);
        const int t00 = ((int)M0 & 1023) + wm * 64 + quad * 4;
        const int hd00 = (bx & 3) * 256 + wn * 32;
#pragma unroll
        for (int Bh = 0; Bh < 2; ++Bh)
#pragma unroll
            for (int nt = 0; nt < 2; ++nt) {
                const int hd = hd00 + Bh * 128 + nt * 16 + l16;
                const int h = hd >> 6, d = hd & 63;
                short* dp = dst + (long)(b * 16 + h) * 65536 + d;
#pragma unroll
                for (int mt = 0; mt < 4; ++mt)
#pragma unroll
                    for (int r = 0; r < 4; ++r)
                        dp[(long)(t00 + mt * 16 + r) * 64] = f2bf(acc[Bh][mt][nt][r]);
            }
    } else {
        // V: per-wave LDS transpose -> vT [bh][d][t], coalesced 16B stores
        short* vT = reinterpret_cast<short*>(z ? o1c : o0c);
        const int b = (int)(M0 >> 10);
        const int hd00 = (bx - 8) * 256 + wn * 32;
        short* ws = smem + w * 2304;     // 32 cols x 72 shorts, wave-private
        const int c8 = (lane & 7) * 8;
        const int colr = lane >> 3;
        const int tb = ((int)M0 & 1023) + wm * 64 + c8;
#pragma unroll
        for (int Bh = 0; Bh < 2; ++Bh) {
#pragma unroll
            for (int nt = 0; nt < 2; ++nt)
#pragma unroll
                for (int mt = 0; mt < 4; ++mt) {
                    uint2 uu;
                    uu.x = pk2(acc[Bh][mt][nt][0], acc[Bh][mt][nt][1]);
                    uu.y = pk2(acc[Bh][mt][nt][2], acc[Bh][mt][nt][3]);
                    *reinterpret_cast<uint2*>(&ws[(nt * 16 + l16) * 72 + mt * 16 + quad * 4]) = uu;
                }
#pragma unroll
            for (int q4 = 0; q4 < 4; ++q4) {
                const int col = q4 * 8 + colr;
                const int hd = hd00 + Bh * 128 + col;
                const int h = hd >> 6, d = hd & 63;
                short8 v = *reinterpret_cast<const short8*>(&ws[col * 72 + c8]);
                *reinterpret_cast<short8*>(&vT[(long)(b * 16 + h) * 65536 + (long)d * 1024 + tb]) = v;
            }
        }
    }
#undef SA128
#undef SB128
#undef RDA128
#undef RDB128
#undef MM128
}

// ---------------- out-proj GEMM: 128x128, TRIPLE-buffer counted-vmcnt pipeline ----------------
// (unchanged — passed in rounds 4-12)
__global__ __launch_bounds__(256)
void gemm_out(const bf16* __restrict__ A0g, const bf16* __restrict__ B0g, float* __restrict__ C0,
              const bf16* __restrict__ A1g, const bf16* __restrict__ B1g, float* __restrict__ C1) {
    __shared__ short smem2[24576];   // 3 bufs x (A 4096 + B 4096)
    const int z = blockIdx.z;
    const short* A = reinterpret_cast<const short*>(z ? A1g : A0g);
    const short* B = reinterpret_cast<const short*>(z ? B1g : B0g);
    const int tid  = threadIdx.x;
    const int lane = tid & 63;
    const int w    = tid >> 6;
    const int wr   = w >> 1;
    const int wc   = w & 1;
    const int quad = lane >> 4;
    const int l16  = lane & 15;
    const long bM = (long)blockIdx.y * 128;

    f32x4 acc[4][4] = {};

    const int sr  = lane >> 2;
    const int scs = ((lane & 3) ^ (sr & 3)) * 8;
    const short* Ag0 = A + (bM + 32 * w + sr) * 1024 + scs;
    const short* Ag1 = Ag0 + 16 * 1024;
    const short* Bg0 = B + ((long)blockIdx.x * 128 + 32 * w + sr) * 1024 + scs;
    const short* Bg1 = Bg0 + 16 * 1024;
    const int sq = (quad ^ (l16 & 3)) * 8;

    {   // prologue: tile 0 -> buf 0
        short* sb = smem2;
        gload16(Ag0, sb + w * 1024);
        gload16(Ag1, sb + w * 1024 + 512);
        gload16(Bg0, sb + 4096 + w * 1024);
        gload16(Bg1, sb + 4096 + w * 1024 + 512);
    }

    int bcur = 0;
#pragma unroll 1
    for (int iter = 0; iter < 32; ++iter) {
        int bnext = bcur + 1; if (bnext == 3) bnext = 0;
        if (iter < 31) {
            const int koff = (iter + 1) * 32;
            short* sb = smem2 + bnext * 8192;
            gload16(Ag0 + koff, sb + w * 1024);
            gload16(Ag1 + koff, sb + w * 1024 + 512);
            gload16(Bg0 + koff, sb + 4096 + w * 1024);
            gload16(Bg1 + koff, sb + 4096 + w * 1024 + 512);
            asm volatile("s_waitcnt vmcnt(4)" ::: "memory");
        } else {
            asm volatile("s_waitcnt vmcnt(0)" ::: "memory");
        }
        __builtin_amdgcn_s_barrier();
        __builtin_amdgcn_sched_barrier(0);

        const short* Ab = smem2 + bcur * 8192;
        const short* Bb = Ab + 4096;

        short8 af[4], bfr[4];
#pragma unroll
        for (int mt = 0; mt < 4; ++mt)
            af[mt] = *reinterpret_cast<const short8*>(&Ab[(wr * 64 + mt * 16 + l16) * 32 + sq]);
#pragma unroll
        for (int nt = 0; nt < 4; ++nt)
            bfr[nt] = *reinterpret_cast<const short8*>(&Bb[(wc * 64 + nt * 16 + l16) * 32 + sq]);
        __builtin_amdgcn_s_setprio(1);
#pragma unroll
        for (int mt = 0; mt < 4; ++mt)
#pragma unroll
            for (int nt = 0; nt < 4; ++nt)
                acc[mt][nt] = MFMA_BF16(af[mt], bfr[nt], acc[mt][nt]);
        __builtin_amdgcn_s_setprio(0);
        bcur = bnext;
    }

    float* C = z ? C1 : C0;
    const long crow = bM + wr * 64 + quad * 4;
    const long ccol = (long)blockIdx.x * 128 + wc * 64 + l16;
#pragma unroll
    for (int mt = 0; mt < 4; ++mt)
#pragma unroll
        for (int nt = 0; nt < 4; ++nt)
#pragma unroll
            for (int r = 0; r < 4; ++r)
                C[(crow + mt * 16 + r) * 1024L + ccol + nt * 16] = acc[mt][nt][r];
}

// ---------------- flash attention: 2 Q-tiles per block (K/V frag reuse), 3-buf counted gate ----------------
// (unchanged — passed in round 12)
__global__ __launch_bounds__(256, 2)
void attn_kernel(const bf16* __restrict__ q0g, const bf16* __restrict__ k0g,
                 const bf16* __restrict__ v0g, bf16* __restrict__ o0g,
                 const bf16* __restrict__ q1g, const bf16* __restrict__ k1g,
                 const bf16* __restrict__ v1g, bf16* __restrict__ o1g) {
    __shared__ short smem[24576];   // 3 bufs x (K 4096 + V 4096) shorts = 48KB
    const int bh = blockIdx.x;
    const int qt0 = blockIdx.y << 1;   // Q-tile pair
    const int z = blockIdx.z;
    const int b = bh >> 4, h = bh & 15;
    const int tid = threadIdx.x, lane = tid & 63, w = tid >> 6;
    const int quad = lane >> 4, l16 = lane & 15;

    const short* Qb = reinterpret_cast<const short*>(z ? q1g : q0g) + (long)bh * 1024 * 64;
    const short* Kb = reinterpret_cast<const short*>(z ? k1g : k0g) + (long)bh * 1024 * 64;
    const short* Vb = reinterpret_cast<const short*>(z ? v1g : v0g) + (long)bh * 64 * 1024;
    short* Ob = reinterpret_cast<short*>(z ? o1g : o0g);

    short8 qb[2][2][2];
#pragma unroll
    for (int q2 = 0; q2 < 2; ++q2)
#pragma unroll
        for (int qg = 0; qg < 2; ++qg) {
            const short* Qp = Qb + (long)((qt0 + q2) * 128 + qg * 64 + w * 16 + l16) * 64;
            qb[q2][qg][0] = *reinterpret_cast<const short8*>(Qp + quad * 8);
            qb[q2][qg][1] = *reinterpret_cast<const short8*>(Qp + 32 + quad * 8);
        }

    // staging: rows 16w+r8 (bit3=0, f=r8&3) and 16w+8+r8 (bit3=1, f=(r8&3)|4)
    const int r8  = lane >> 3;
    const int sc0 = ((lane & 7) ^ (r8 & 3)) * 8;
    const short* Kg0 = Kb + (long)(16 * w + r8) * 64 + sc0;
    const short* Kg1 = Kb + (long)(16 * w + 8 + r8) * 64 + (sc0 ^ 32);
    const short* Vg0 = Vb + (long)(16 * w + r8) * 1024 + sc0;
    const short* Vg1 = Vb + (long)(16 * w + 8 + r8) * 1024 + (sc0 ^ 32);

    const int jbase = 8 * (l16 >> 2) + (l16 & 3);
    // read-side swizzle constants (row bits expressed via l16)
    const int fKs = (l16 & 3) | (((l16 >> 2) & 1) << 2);
    const int s0  = (quad ^ fKs) * 8;
    const int fVs = (l16 & 3) | (((l16 >> 3) & 1) << 2);
    const int sv  = (quad ^ fVs) * 8;

    f32x4 o[2][2][4] = {};
    float li[2][2] = {{0.f, 0.f}, {0.f, 0.f}};

    // prologue: tile 0 -> buf 0
    gload16(Kg0, smem + w * 1024); gload16(Kg1, smem + w * 1024 + 512);
    gload16(Vg0, smem + 4096 + w * 1024); gload16(Vg1, smem + 4096 + w * 1024 + 512);

    int bcur = 0;
#pragma unroll 1
    for (int iter = 0; iter < 16; ++iter) {
        int bnext = bcur + 1; if (bnext == 3) bnext = 0;
        if (iter < 15) {   // stage tile t+1 into beta(t+1)
            short* sb = smem + bnext * 8192;
            const long ko = (long)(iter + 1) * 4096;   // K: 64 t-rows * 64 shorts
            const long vo = (long)(iter + 1) * 64;     // V: within-row t offset
            gload16(Kg0 + ko, sb + w * 1024);
            gload16(Kg1 + ko, sb + w * 1024 + 512);
            gload16(Vg0 + vo, sb + 4096 + w * 1024);
            gload16(Vg1 + vo, sb + 4096 + w * 1024 + 512);
            asm volatile("s_waitcnt vmcnt(4)" ::: "memory");
        } else {
            asm volatile("s_waitcnt vmcnt(0)" ::: "memory");
        }
        __builtin_amdgcn_s_barrier();
        __builtin_amdgcn_sched_barrier(0);

        const short* Ks = smem + bcur * 8192;
        const short* Vs = Ks + 4096;

        // K-frags once, reused for both Q-tiles
        short8 kf[4][2];
#pragma unroll
        for (int g = 0; g < 4; ++g) {
            const int goff = (g >> 1) * 32 + (g & 1) * 4;
            const short* kr = Ks + (jbase + goff) * 64;
            kf[g][0] = *reinterpret_cast<const short8*>(kr + s0);
            kf[g][1] = *reinterpret_cast<const short8*>(kr + (s0 ^ 32));
        }

        union { unsigned int u[4]; short8 s; } f0[2][2], f1[2][2];
#pragma unroll
        for (int q2 = 0; q2 < 2; ++q2) {
            f32x4 st[2][4];
            __builtin_amdgcn_s_setprio(1);
#pragma unroll
            for (int g = 0; g < 4; ++g)
#pragma unroll
                for (int qg = 0; qg < 2; ++qg) {
                    f32x4 zf = {0.f, 0.f, 0.f, 0.f};
                    zf = MFMA_BF16(kf[g][0], qb[q2][qg][0], zf);
                    zf = MFMA_BF16(kf[g][1], qb[q2][qg][1], zf);
                    st[qg][g] = zf;
                }
            __builtin_amdgcn_s_setprio(0);

#pragma unroll
            for (int qg = 0; qg < 2; ++qg) {
                float p[4][4];
                float rs = 0.f;
#pragma unroll
                for (int g = 0; g < 4; ++g)
#pragma unroll
                    for (int r = 0; r < 4; ++r) {
                        float e = EXP2F(st[qg][g][r]);
                        p[g][r] = e;
                        rs += e;
                    }
                li[q2][qg] += rs;
                f0[q2][qg].u[0] = pk2(p[0][0], p[0][1]); f0[q2][qg].u[1] = pk2(p[0][2], p[0][3]);
                f0[q2][qg].u[2] = pk2(p[1][0], p[1][1]); f0[q2][qg].u[3] = pk2(p[1][2], p[1][3]);
                f1[q2][qg].u[0] = pk2(p[2][0], p[2][1]); f1[q2][qg].u[1] = pk2(p[2][2], p[2][3]);
                f1[q2][qg].u[2] = pk2(p[3][0], p[3][1]); f1[q2][qg].u[3] = pk2(p[3][2], p[3][3]);
            }
        }

        // V-frags once, reused for both Q-tiles
        __builtin_amdgcn_s_setprio(1);
#pragma unroll
        for (int dt = 0; dt < 4; ++dt) {
            const short* vr = Vs + (dt * 16 + l16) * 64;
            short8 v0 = *reinterpret_cast<const short8*>(vr + sv);
            short8 v1 = *reinterpret_cast<const short8*>(vr + (sv ^ 32));
#pragma unroll
            for (int q2 = 0; q2 < 2; ++q2)
#pragma unroll
                for (int qg = 0; qg < 2; ++qg) {
                    o[q2][qg][dt] = MFMA_BF16(v0, f0[q2][qg].s, o[q2][qg][dt]);
                    o[q2][qg][dt] = MFMA_BF16(v1, f1[q2][qg].s, o[q2][qg][dt]);
                }
        }
        __builtin_amdgcn_s_setprio(0);
        bcur = bnext;
    }

    __syncthreads();   // O-staging below reuses smem regions that overlap K/V bufs

#pragma unroll
    for (int q2 = 0; q2 < 2; ++q2)
#pragma unroll
        for (int qg = 0; qg < 2; ++qg) {
            li[q2][qg] += __shfl_xor(li[q2][qg], 16);
            li[q2][qg] += __shfl_xor(li[q2][qg], 32);
        }

#pragma unroll
    for (int q2 = 0; q2 < 2; ++q2)
#pragma unroll
        for (int qg = 0; qg < 2; ++qg) {
            short* Os = smem + qg * 5120 + w * 1280;   // wave-private; same-wave DS ordering
            const float rl = 1.0f / li[q2][qg];
#pragma unroll
            for (int dt = 0; dt < 4; ++dt) {
                uint2 uu;
                uu.x = pk2(o[q2][qg][dt][0] * rl, o[q2][qg][dt][1] * rl);
                uu.y = pk2(o[q2][qg][dt][2] * rl, o[q2][qg][dt][3] * rl);
                *reinterpret_cast<uint2*>(&Os[l16 * 80 + dt * 16 + quad * 4]) = uu;
            }
#pragma unroll
            for (int p = 0; p < 2; ++p) {
                int row = p * 8 + (lane >> 3);
                int ch = (lane & 7) * 8;
                short8 v = *reinterpret_cast<const short8*>(&Os[row * 80 + ch]);
                *reinterpret_cast<short8*>(&Ob[((long)(b * 1024) + (qt0 + q2) * 128 + qg * 64 + w * 16 + row) * 1024 + h * 64 + ch]) = v;
            }
        }
}

extern "C" void kernel_launch(void* const* d_in, const int* in_sizes, int n_in,
                              void* d_out, int out_size, void* d_ws, size_t ws_size,
                              hipStream_t stream) {
    const float* x     = (const float*)d_in[0];
    const float* y     = (const float*)d_in[1];
    const float* Wqkv1 = (const float*)d_in[2];
    const float* Wqkv2 = (const float*)d_in[3];
    const float* Wout1 = (const float*)d_in[4];
    const float* Wout2 = (const float*)d_in[5];

    char* ws = (char*)d_ws;
    bf16* Wqkv1b = (bf16*)(ws + 0);          // 6291456
    bf16* Wqkv2b = (bf16*)(ws + 6291456);    // 6291456
    bf16* Wout1b = (bf16*)(ws + 12582912);   // 2097152
    bf16* Wout2b = (bf16*)(ws + 14680064);   // 2097152
    bf16* xb     = (bf16*)(ws + 16777216);   // 8388608
    bf16* yb     = (bf16*)(ws + 25165824);   // 8388608
    bf16* q1     = (bf16*)(ws + 33554432);   // 8388608  packed [bh][t][d]
    bf16* k1     = (bf16*)(ws + 41943040);   // 8388608
    bf16* v1T    = (bf16*)(ws + 50331648);   // 8388608  [bh][d][t]
    bf16* q2     = (bf16*)(ws + 58720256);   // 8388608
    bf16* k2     = (bf16*)(ws + 67108864);   // 8388608
    bf16* v2T    = (bf16*)(ws + 75497472);   // 8388608 -> 83886080 (80 MB)
    bf16* xo     = xb;                       // xb dead after qkv GEMM
    bf16* yo     = yb;

    static bool s_attr = false;
    if (!s_attr) {
        (void)hipFuncSetAttribute(reinterpret_cast<const void*>(&gemm_qkv128),
                                  hipFuncAttributeMaxDynamicSharedMemorySize, 147456);
        s_attr = true;
    }

    // 1. all converts (compact 1D grid; x, y, Wout, Wqkv-permuted+scaled)
    cvt_fused<<<dim3(16384), 256, 0, stream>>>(x, y, Wout1, Wout2, Wqkv1, Wqkv2,
                                               xb, yb, Wout1b, Wout2b, Wqkv1b, Wqkv2b);

    // 2. qkv GEMM: 128x256 triple-buffer single-gate pipeline + bijective XCD swizzle
    gemm_qkv128<<<dim3(12, 32, 2), 512, 147456, stream>>>(xb, Wqkv1b, q1, k1, v1T,
                                                          yb, Wqkv2b, q2, k2, v2T);

    // 3. cross attention (2 Q-tiles/block): z=0: softmax(q2 k1^T) v1 -> xo ; z=1: ... -> yo
    attn_kernel<<<dim3(64, 4, 2), 256, 0, stream>>>(q2, k1, v1T, xo,
                                                    q1, k2, v2T, yo);

    // 4. output projections (triple-buffer counted-vmcnt pipeline, fp32 epilogue)
    gemm_out<<<dim3(8, 32, 2), 256, 0, stream>>>(xo, Wout1b, (float*)d_out,
                                                 yo, Wout2b, ((float*)d_out) + 4194304);
}